// Round 6
// baseline (470.688 us; speedup 1.0000x reference)
//
#include <hip/hip_runtime.h>
#include <math.h>
#include <stdint.h>

typedef unsigned short u16;
typedef __bf16 bf16x8 __attribute__((ext_vector_type(8)));
typedef float f32x4 __attribute__((ext_vector_type(4)));

typedef const __attribute__((address_space(1))) void gv_t;
typedef __attribute__((address_space(3))) void lv_t;

__device__ __forceinline__ u16 f2bf(float f) {
    unsigned u = __builtin_bit_cast(unsigned, f);
    return (u16)((u + 0x7FFFu + ((u >> 16) & 1u)) >> 16);
}
__device__ __forceinline__ float bf2f(u16 h) {
    return __builtin_bit_cast(float, (unsigned)h << 16);
}
// async global->LDS, 16B per lane; LDS dest = wave-uniform base + lane*16
__device__ __forceinline__ void gll16(const void* g, void* l) {
    __builtin_amdgcn_global_load_lds((gv_t*)(uintptr_t)g,
                                     (lv_t*)(unsigned)(uintptr_t)l, 16, 0, 0);
}

// ---------------- fused conversions: hidden fp32->bf16 + 4 weight transposes ----
// blocks [0,8192): hidden cvt (float4 per lane). blocks [8192,9216): weight
// fp32 [1024][N] -> bf16 [N][1024] transpose via 64x64 LDS tile.
__global__ __launch_bounds__(256) void cvt_all_kernel(
    const float* __restrict__ hidden, u16* __restrict__ hb,
    const float* __restrict__ w0, const float* __restrict__ w1,
    const float* __restrict__ w2, const float* __restrict__ w3,
    u16* __restrict__ o0, u16* __restrict__ o1,
    u16* __restrict__ o2, u16* __restrict__ o3)
{
    __shared__ u16 t[64][65];
    int bid = blockIdx.x, tid = threadIdx.x;
    if (bid < 8192) {
        int i = bid * 256 + tid;
        float4 f = ((const float4*)hidden)[i];
        ushort4 o = make_ushort4(f2bf(f.x), f2bf(f.y), f2bf(f.z), f2bf(f.w));
        ((ushort4*)hb)[i] = o;
        return;
    }
    int id2 = bid - 8192;                 // 1024 t4 blocks
    int bz = id2 >> 8, by = (id2 >> 4) & 15, bx = id2 & 15;
    const float* in; u16* out; int N;
    switch (bz) {
        case 0: in = w0; out = o0; N = 1024; break;
        case 1: in = w1; out = o1; N = 512;  break;
        case 2: in = w2; out = o2; N = 512;  break;
        default: in = w3; out = o3; N = 1024; break;
    }
    int kb = by * 64, nb = bx * 64;
    if (nb >= N) return;
#pragma unroll
    for (int c = 0; c < 16; ++c) {
        int id = c * 256 + tid;
        int r = id >> 6, n = id & 63;
        t[n][r] = f2bf(in[(size_t)(kb + r) * N + nb + n]);
    }
    __syncthreads();
#pragma unroll
    for (int c = 0; c < 16; ++c) {
        int id = c * 256 + tid;
        int r = id >> 6, n = id & 63;
        out[(size_t)(nb + r) * 1024 + kb + n] = t[r][n];
    }
}

// ---------------- MFMA GEMM body, BK=64, 2-phase dbuf, XOR-swizzled DMA -----
// A: [8192][K] bf16, Bt: [N][K] bf16. 128x128 tile, 256 thr = 4 waves 2x2.
// Unified T3 2-phase pipeline: prologue stages tile 0; per tile: __syncthreads
// (drains tile t's DMA, which flew during tile t-1's compute) -> issue t+1 ->
// ds_read + MFMA. LDS 64 KB -> 2 blocks/CU.
// XCD-chunked remap: hw id%8 = XCD; contiguous nid chunk per XCD so blocks
// sharing A-panels co-locate with the B panel in one 4 MiB L2.
// MODE 0: fused QKV, N=2048; K-columns get RoPE applied IN-EPILOGUE (lanes
// l16 and l16^1 hold the interleaved pair; __shfl_xor(1) exchanges them).
// MODE 1: N=1024, fp32 out Cf = acc + b0 + resid.
template<int MODE, int NBX>
__device__ __forceinline__ void gemm_body(
    const u16* __restrict__ A, const u16* __restrict__ Bt,
    const float* __restrict__ b0, const float* __restrict__ b1,
    const float* __restrict__ b2,
    const float* __restrict__ resid, float* __restrict__ Cf,
    u16* __restrict__ Qo, u16* __restrict__ Ko, u16* __restrict__ Vto,
    int N, int K)
{
    __shared__ __align__(16) u16 Asl[2][128 * 64];
    __shared__ __align__(16) u16 Bsl[2][128 * 64];
    const int tid = threadIdx.x, lane = tid & 63, w = tid >> 6;
    const int quad = lane >> 4, l16 = lane & 15;
    const int id = blockIdx.x;
    const int chunk = (NBX * 64) >> 3;                // blocks per XCD
    const int nid = (id & 7) * chunk + (id >> 3);     // id%8 -> XCD
    const int bx = nid & (NBX - 1), by = nid / NBX;
    const int bm = by * 128, bn = bx * 128;
    const int wm = (w >> 1) * 64, wn = (w & 1) * 64;

    f32x4 acc[4][4] = {};

    const int dr = lane >> 3;                       // row within 8-row band
    const int dcs = (((lane & 7) ^ dr) << 3);       // swizzled global chunk (elems)
    const u16* Ag = &A[(size_t)(bm + w * 32 + dr) * K + dcs];
    const u16* Bg = &Bt[(size_t)(bn + w * 32 + dr) * K + dcs];

    const int sw = l16 & 7;  // fragment-read swizzle

    const int NT = K >> 6;
#pragma unroll
    for (int c = 0; c < 4; ++c) {  // prologue: stage tile 0 -> buf 0
        gll16(Ag + (size_t)(c * 8) * K, &Asl[0][(w * 32 + c * 8) * 64]);
        gll16(Bg + (size_t)(c * 8) * K, &Bsl[0][(w * 32 + c * 8) * 64]);
    }
    for (int t = 0; t < NT; ++t) {
        const int cur = t & 1;
        // drains this wave's outstanding DMA (tile t, issued during the
        // previous tile's compute) + barrier -> tile t staged everywhere.
        __syncthreads();
        if (t < NT - 1) {
            const int k0 = (t + 1) * 64;
#pragma unroll
            for (int c = 0; c < 4; ++c) {
                gll16(Ag + (size_t)(c * 8) * K + k0, &Asl[cur ^ 1][(w * 32 + c * 8) * 64]);
                gll16(Bg + (size_t)(c * 8) * K + k0, &Bsl[cur ^ 1][(w * 32 + c * 8) * 64]);
            }
        }
        bf16x8 af[4][2], bfr[4][2];
#pragma unroll
        for (int i = 0; i < 4; ++i)
#pragma unroll
            for (int ks = 0; ks < 2; ++ks)
                af[i][ks] = *(const bf16x8*)&Asl[cur][(wm + i * 16 + l16) * 64 + (((ks * 4 + quad) ^ sw) << 3)];
#pragma unroll
        for (int j = 0; j < 4; ++j)
#pragma unroll
            for (int ks = 0; ks < 2; ++ks)
                bfr[j][ks] = *(const bf16x8*)&Bsl[cur][(wn + j * 16 + l16) * 64 + (((ks * 4 + quad) ^ sw) << 3)];
#pragma unroll
        for (int i = 0; i < 4; ++i)
#pragma unroll
            for (int j = 0; j < 4; ++j)
#pragma unroll
                for (int ks = 0; ks < 2; ++ks)
                    acc[i][j] = __builtin_amdgcn_mfma_f32_16x16x32_bf16(af[i][ks], bfr[j][ks], acc[i][j], 0, 0, 0);
        // no trailing barrier: next iteration's __syncthreads covers the
        // read-before-overwrite hazard (prefetch targets the other buffer).
    }

    // epilogue: C/D layout col=lane&15, row=quad*4+reg
#pragma unroll
    for (int j = 0; j < 4; ++j) {
        int col = bn + wn + j * 16 + l16;
        if (MODE == 1) {
            float bb = b0[col];
#pragma unroll
            for (int i = 0; i < 4; ++i) {
                int row0 = bm + wm + i * 16 + quad * 4;
#pragma unroll
                for (int r = 0; r < 4; ++r) {
                    size_t off = (size_t)(row0 + r) * N + col;
                    Cf[off] = acc[i][j][r] + bb + resid[off];
                }
            }
        } else if (col < 1024) {
            float bb = b0[col];
#pragma unroll
            for (int i = 0; i < 4; ++i) {
                int row0 = bm + wm + i * 16 + quad * 4;
#pragma unroll
                for (int r = 0; r < 4; ++r)
                    Qo[(size_t)(row0 + r) * 1024 + col] = f2bf(acc[i][j][r] + bb);
            }
        } else if (col < 1536) {
            // K columns: apply RoPE in-epilogue. All 64 lanes of the wave are
            // in this branch together (col depends only on l16, boundaries are
            // 16-aligned). Lanes l16 even/odd hold the (x1,x2) interleaved
            // pair; __shfl_xor(.,1) exchanges partners within the wave.
            int c2 = col - 1024;
            float bb = b1[c2];
            int jj = (c2 & 63) >> 1;
            float inv = exp2f((float)jj * -0.4152410118609203f);  // 10000^(-2j/64)
            float sgn = (l16 & 1) ? 1.0f : -1.0f;
#pragma unroll
            for (int i = 0; i < 4; ++i) {
                int row0 = bm + wm + i * 16 + quad * 4;
#pragma unroll
                for (int r = 0; r < 4; ++r) {
                    float v = acc[i][j][r] + bb;
                    float o = __shfl_xor(v, 1);
                    float sn, cs;
                    sincosf((float)((row0 + r) & 1023) * inv, &sn, &cs);
                    // even lane: v*cs - o*sn ; odd lane: v*cs + o*sn
                    Ko[(size_t)(row0 + r) * 512 + c2] = f2bf(fmaf(v, cs, sgn * (o * sn)));
                }
            }
        } else {
            int c2 = col - 1536, kvh = c2 >> 6, d = c2 & 63;
            float bb = b2[c2];
#pragma unroll
            for (int i = 0; i < 4; ++i) {
                int row0 = bm + wm + i * 16 + quad * 4;
                int b = row0 >> 10, s = row0 & 1023;
                ushort4 o4;
                o4.x = f2bf(acc[i][j][0] + bb);
                o4.y = f2bf(acc[i][j][1] + bb);
                o4.z = f2bf(acc[i][j][2] + bb);
                o4.w = f2bf(acc[i][j][3] + bb);
                *(ushort4*)&Vto[(size_t)((b * 8 + kvh) * 64 + d) * 1024 + s] = o4;
            }
        }
    }
}

// Distinct kernel names so rocprof rows are unambiguous per mode.
__global__ __launch_bounds__(256) void gemm_qkv(
    const u16* __restrict__ A, const u16* __restrict__ Bt,
    const float* __restrict__ b0, const float* __restrict__ b1,
    const float* __restrict__ b2,
    u16* __restrict__ Qo, u16* __restrict__ Ko, u16* __restrict__ Vto)
{
    gemm_body<0, 16>(A, Bt, b0, b1, b2, nullptr, nullptr, Qo, Ko, Vto, 2048, 1024);
}

__global__ __launch_bounds__(256) void gemm_out(
    const u16* __restrict__ A, const u16* __restrict__ Bt,
    const float* __restrict__ b0,
    const float* __restrict__ resid, float* __restrict__ Cf)
{
    gemm_body<1, 8>(A, Bt, b0, nullptr, nullptr, resid, Cf,
                    nullptr, nullptr, nullptr, 1024, 1024);
}

// ---------------- MFMA flash attention: 128 q/block, fused Q-RoPE -----------
// R4-proven version (54.1 us): Ps LDS bounce kept — R5 showed removing it
// regresses (the compiler hides the Ps chain; split b64 V-reads cost more).
// Q: [8192][1024] bf16 (h*64+d, UNroped). K: [8192][512] (kvh*64+d, roped).
// Vt: [(b*8+kvh)*64+d][1024 keys] bf16 (pre-transposed).
// T3 2-phase: double-buffered Ks/Vts, one __syncthreads per tile (its vmcnt(0)
// drain is exactly tile kt's DMA, in flight during kt-1's compute).
// Ps [64][40]: PV is q-group-serial with V fragments cached in regs; each wave
// time-shares a 16-row Ps band (in-wave LDS ordering, no barrier).
// LDS 37.9 KB -> 4 blocks/CU; grid 1024 = 256 CU x 4 fully co-resident.
// XCD-chunked swizzle: each batch b (K+V 2.1 MB) pinned to one XCD L2
// (verified R4: FETCH 74 -> 16.5 MB).
__global__ __launch_bounds__(256, 4) void attn_mfma(
    const u16* __restrict__ Q, const u16* __restrict__ K,
    const u16* __restrict__ Vt, u16* __restrict__ O)
{
    __shared__ __align__(16) u16 Ks[2][64 * 64];   // [buf][key][d], swizzled chunks
    __shared__ __align__(16) u16 Vts[2][64 * 64];  // [buf][d][key], swizzled chunks
    __shared__ __align__(16) u16 Ps[64][40];       // [wave 16-row band][32 keys + pad]

    const int tid = threadIdx.x, lane = tid & 63, w = tid >> 6;
    const int quad = lane >> 4, l16 = lane & 15;
    const int id = blockIdx.x;
    const int nid = (id & 7) * 128 + (id >> 3);    // XCD-chunked (id%8 -> XCD)
    const int qt = nid & 7, h = (nid >> 3) & 15, b = nid >> 7;
    const int kvh = h >> 1;
    const size_t qrow0 = (size_t)b * 1024 + qt * 128;
    const size_t krow0 = (size_t)b * 1024;
    const u16* Vg = Vt + (size_t)((b * 8 + kvh) * 64) * 1024;

    // DMA staging: per wave 16 rows each of K,V^T; 2 calls of 8 rows each.
    const int dr = lane >> 3;                    // row in 8-row band
    const int dcs = (((lane & 7) ^ dr) << 3);    // swizzled global chunk (elems)
    const u16* Kg0 = &K[(krow0 + w * 16 + dr) * 512 + kvh * 64 + dcs];
    const u16* Vg0 = &Vg[(size_t)(w * 16 + dr) * 1024 + dcs];
    const int sw = l16 & 7;
    const float C1 = 0.18033688011112043f;  // 0.125 * log2(e), folded into Q

    // prologue: stage tile 0 into buffer 0 (overlaps Q-RoPE prep below)
#pragma unroll
    for (int c = 0; c < 2; ++c) {
        gll16(Kg0 + (size_t)(c * 8) * 512, &Ks[0][(w * 16 + c * 8) * 64]);
        gll16(Vg0 + (size_t)(c * 8) * 1024, &Vts[0][(w * 16 + c * 8) * 64]);
    }

    // Q fragments with RoPE (and softmax scale C1) applied in-register.
    bf16x8 qf[2][2];
#pragma unroll
    for (int qg = 0; qg < 2; ++qg) {
        int qrow = w * 32 + qg * 16 + l16;
        float fpos = (float)(qt * 128 + qrow);
#pragma unroll
        for (int ks = 0; ks < 2; ++ks) {
            uint4 qraw = *(const uint4*)&Q[(qrow0 + qrow) * 1024 + h * 64 + ks * 32 + quad * 8];
            unsigned o_[4];
#pragma unroll
            for (int t = 0; t < 4; ++t) {
                int j = ks * 16 + quad * 4 + t;
                float inv = exp2f((float)j * -0.4152410118609203f);
                float sn_, cs_;
                sincosf(fpos * inv, &sn_, &cs_);
                cs_ *= C1; sn_ *= C1;            // fold softmax scale into Q
                unsigned u = (&qraw.x)[t];
                float x1 = bf2f((u16)(u & 0xffff)), x2 = bf2f((u16)(u >> 16));
                float y1 = x1 * cs_ - x2 * sn_, y2 = x1 * sn_ + x2 * cs_;
                o_[t] = (unsigned)f2bf(y1) | ((unsigned)f2bf(y2) << 16);
            }
            qf[qg][ks] = __builtin_bit_cast(bf16x8, make_uint4(o_[0], o_[1], o_[2], o_[3]));
        }
    }

    f32x4 acc_o[2][4] = {};
    f32x4 lsum[2] = {};  // ones-MFMA row-sum accumulator (all regs equal at end)
    const bf16x8 ones = __builtin_bit_cast(bf16x8,
        make_uint4(0x3F803F80u, 0x3F803F80u, 0x3F803F80u, 0x3F803F80u));

    for (int kt = 0; kt < 16; ++kt) {
        const int cur = kt & 1;
        // drains this wave's outstanding DMA (tile kt, in flight during the
        // previous tile's compute) + barrier -> tile kt staged everywhere.
        __syncthreads();

        // prefetch tile kt+1 into the other buffer; its last reader was
        // compute(kt-1), which precedes this barrier for all waves.
        if (kt < 15) {
#pragma unroll
            for (int c = 0; c < 2; ++c) {
                gll16(Kg0 + (size_t)((kt + 1) * 64 + c * 8) * 512,
                      &Ks[cur ^ 1][(w * 16 + c * 8) * 64]);
                gll16(Vg0 + (size_t)(c * 8) * 1024 + (kt + 1) * 64,
                      &Vts[cur ^ 1][(w * 16 + c * 8) * 64]);
            }
        }

        // S^T = K . Q^T : s[qg][nt] holds keys nt*16+quad*4+(0..3) for q-group qg
        f32x4 s[2][4] = {};
        __builtin_amdgcn_s_setprio(1);
#pragma unroll
        for (int ks = 0; ks < 2; ++ks) {
#pragma unroll
            for (int nt = 0; nt < 4; ++nt) {
                bf16x8 ak = *(const bf16x8*)&Ks[cur][(nt * 16 + l16) * 64 + (((ks * 4 + quad) ^ sw) << 3)];
                s[0][nt] = __builtin_amdgcn_mfma_f32_16x16x32_bf16(ak, qf[0][ks], s[0][nt], 0, 0, 0);
                s[1][nt] = __builtin_amdgcn_mfma_f32_16x16x32_bf16(ak, qf[1][ks], s[1][nt], 0, 0, 0);
            }
        }
        __builtin_amdgcn_s_setprio(0);

        // per key-chunk kc (keys kc*32..+31): softmax -> Ps band, then PV MFMA.
        // Ps band is wave-private AND time-shared across (kc, qg): in-wave LDS
        // ordering guarantees qg0's read completes before qg1's overwrite.
#pragma unroll
        for (int kc = 0; kc < 2; ++kc) {
            bf16x8 av[4];  // V fragments cached: shared by both q-groups
#pragma unroll
            for (int nt = 0; nt < 4; ++nt)
                av[nt] = *(const bf16x8*)&Vts[cur][(nt * 16 + l16) * 64 + (((kc * 4 + quad) ^ sw) << 3)];
#pragma unroll
            for (int qg = 0; qg < 2; ++qg) {
#pragma unroll
                for (int ntl = 0; ntl < 2; ++ntl) {
                    int nt = kc * 2 + ntl;
                    float p0 = __builtin_amdgcn_exp2f(s[qg][nt][0]);
                    float p1 = __builtin_amdgcn_exp2f(s[qg][nt][1]);
                    unsigned pk0 = __builtin_amdgcn_perm(
                        __builtin_bit_cast(unsigned, p1),
                        __builtin_bit_cast(unsigned, p0), 0x07060302u);
                    float p2 = __builtin_amdgcn_exp2f(s[qg][nt][2]);
                    float p3 = __builtin_amdgcn_exp2f(s[qg][nt][3]);
                    unsigned pk1 = __builtin_amdgcn_perm(
                        __builtin_bit_cast(unsigned, p3),
                        __builtin_bit_cast(unsigned, p2), 0x07060302u);
                    *(uint2*)&Ps[w * 16 + l16][ntl * 16 + quad * 4] = make_uint2(pk0, pk1);
                }
                bf16x8 bp = *(const bf16x8*)&Ps[w * 16 + l16][quad * 8];
                __builtin_amdgcn_s_setprio(1);
                // l_i = P . 1 via ones-MFMA (sums the exact bf16 P used by PV)
                lsum[qg] = __builtin_amdgcn_mfma_f32_16x16x32_bf16(ones, bp, lsum[qg], 0, 0, 0);
                // O^T += V^T(chunk kc) . P^T(chunk kc)
#pragma unroll
                for (int nt = 0; nt < 4; ++nt)
                    acc_o[qg][nt] = __builtin_amdgcn_mfma_f32_16x16x32_bf16(av[nt], bp, acc_o[qg][nt], 0, 0, 0);
                __builtin_amdgcn_s_setprio(0);
            }
        }
        // no trailing barrier: next iteration's __syncthreads covers the
        // read-before-overwrite hazard (prefetch targets the other buffer).
    }

    // epilogue: lsum already holds full row sums (all lanes/regs for q=l16)
#pragma unroll
    for (int qg = 0; qg < 2; ++qg) {
        float rl = 1.0f / lsum[qg][0];
        size_t orow = (qrow0 + w * 32 + qg * 16 + l16) * 1024 + h * 64;
#pragma unroll
        for (int nt = 0; nt < 4; ++nt) {
            ushort4 o4;
            o4.x = f2bf(acc_o[qg][nt][0] * rl);
            o4.y = f2bf(acc_o[qg][nt][1] * rl);
            o4.z = f2bf(acc_o[qg][nt][2] * rl);
            o4.w = f2bf(acc_o[qg][nt][3] * rl);
            *(ushort4*)&O[orow + nt * 16 + quad * 4] = o4;
        }
    }
}

// ---------------- LayerNorm in place on [8192][1024] fp32 ----------------
__global__ __launch_bounds__(256) void ln_kernel(float* __restrict__ io,
    const float* __restrict__ gamma, const float* __restrict__ beta)
{
    int row = blockIdx.x;
    int tid = threadIdx.x;
    float* p = io + (size_t)row * 1024;
    float4 x = *reinterpret_cast<const float4*>(&p[tid << 2]);
    float s = x.x + x.y + x.z + x.w;
    float ss = fmaf(x.x, x.x, fmaf(x.y, x.y, fmaf(x.z, x.z, x.w * x.w)));
#pragma unroll
    for (int off = 32; off > 0; off >>= 1) {
        s  += __shfl_down(s, off);
        ss += __shfl_down(ss, off);
    }
    __shared__ float rs[4], rss[4];
    int lane = tid & 63, wid = tid >> 6;
    if (lane == 0) { rs[wid] = s; rss[wid] = ss; }
    __syncthreads();
    float S = rs[0] + rs[1] + rs[2] + rs[3];
    float SS = rss[0] + rss[1] + rss[2] + rss[3];
    float mu = S * (1.0f / 1024.0f);
    float var = SS * (1.0f / 1024.0f) - mu * mu;
    float rstd = rsqrtf(var + 1e-12f);
    float4 g = *reinterpret_cast<const float4*>(&gamma[tid << 2]);
    float4 be = *reinterpret_cast<const float4*>(&beta[tid << 2]);
    float4 o;
    o.x = (x.x - mu) * rstd * g.x + be.x;
    o.y = (x.y - mu) * rstd * g.y + be.y;
    o.z = (x.z - mu) * rstd * g.z + be.z;
    o.w = (x.w - mu) * rstd * g.w + be.w;
    *reinterpret_cast<float4*>(&p[tid << 2]) = o;
}

// ---------------- launch ----------------
extern "C" void kernel_launch(void* const* d_in, const int* in_sizes, int n_in,
                              void* d_out, int out_size, void* d_ws, size_t ws_size,
                              hipStream_t stream)
{
    (void)in_sizes; (void)n_in; (void)out_size; (void)ws_size;
    const float* hidden = (const float*)d_in[0];
    const float* Wq = (const float*)d_in[1];
    const float* bq = (const float*)d_in[2];
    const float* Wk = (const float*)d_in[3];
    const float* bk = (const float*)d_in[4];
    const float* Wv = (const float*)d_in[5];
    const float* bv = (const float*)d_in[6];
    const float* Wo = (const float*)d_in[7];
    const float* bo = (const float*)d_in[8];
    const float* g  = (const float*)d_in[9];
    const float* be = (const float*)d_in[10];
    float* out = (float*)d_out;

    // workspace layout (Wqt/Wkt/Wvt contiguous => one [2048][1024] B^T matrix)
    u16* hb  = (u16*)d_ws;                       // [8192][1024] bf16 hidden
    u16* Wqt = hb  + (size_t)8192 * 1024;        // [1024][1024] Wq^T
    u16* Wkt = Wqt + (size_t)1024 * 1024;        // [512][1024]  Wk^T
    u16* Wvt = Wkt + (size_t)512 * 1024;         // [512][1024]  Wv^T
    u16* Wot = Wvt + (size_t)512 * 1024;         // [1024][1024] Wo^T
    u16* Qb  = Wot + (size_t)1024 * 1024;        // [8192][1024] Q (then attn out)
    u16* Kb  = Qb  + (size_t)8192 * 1024;        // [8192][512]  K (roped in-epilogue)
    u16* Vtb = Kb  + (size_t)8192 * 512;         // [4096][1024] V^T per (b,kvh)
    // total ~66 MB

    cvt_all_kernel<<<9216, 256, 0, stream>>>(hidden, hb, Wq, Wk, Wv, Wo,
                                             Wqt, Wkt, Wvt, Wot);

    // fused QKV: N=2048 (Bt = [Wq^T;Wk^T;Wv^T]); writes Qb (unroped),
    // Kb (ROPED in epilogue), Vtb (V transposed)
    gemm_qkv<<<dim3(1024), 256, 0, stream>>>(hb, Wqt, bq, bk, bv, Qb, Kb, Vtb);

    attn_mfma<<<dim3(1024), 256, 0, stream>>>(Qb, Kb, Vtb, Qb);

    // out-proj: fp32 out + bias + resid, 2-phase pipelined
    gemm_out<<<dim3(512), 256, 0, stream>>>(Qb, Wot, bo, hidden, out);

    ln_kernel<<<8192, 256, 0, stream>>>(out, g, be);
}

// Round 7
// 234.128 us; speedup vs baseline: 2.0104x; 2.0104x over previous
//
#include <hip/hip_runtime.h>
#include <math.h>
#include <stdint.h>

typedef unsigned short u16;
typedef __bf16 bf16x8 __attribute__((ext_vector_type(8)));
typedef float f32x4 __attribute__((ext_vector_type(4)));

typedef const __attribute__((address_space(1))) void gv_t;
typedef __attribute__((address_space(3))) void lv_t;

__device__ __forceinline__ u16 f2bf(float f) {
    unsigned u = __builtin_bit_cast(unsigned, f);
    return (u16)((u + 0x7FFFu + ((u >> 16) & 1u)) >> 16);
}
__device__ __forceinline__ float bf2f(u16 h) {
    return __builtin_bit_cast(float, (unsigned)h << 16);
}
// async global->LDS, 16B per lane; LDS dest = wave-uniform base + lane*16
__device__ __forceinline__ void gll16(const void* g, void* l) {
    __builtin_amdgcn_global_load_lds((gv_t*)(uintptr_t)g,
                                     (lv_t*)(unsigned)(uintptr_t)l, 16, 0, 0);
}

// ---------------- fused conversions: hidden fp32->bf16 + 4 weight transposes ----
// blocks [0,8192): hidden cvt (float4 per lane). blocks [8192,9216): weight
// fp32 [1024][N] -> bf16 [N][1024] transpose via 64x64 LDS tile.
__global__ __launch_bounds__(256) void cvt_all_kernel(
    const float* __restrict__ hidden, u16* __restrict__ hb,
    const float* __restrict__ w0, const float* __restrict__ w1,
    const float* __restrict__ w2, const float* __restrict__ w3,
    u16* __restrict__ o0, u16* __restrict__ o1,
    u16* __restrict__ o2, u16* __restrict__ o3)
{
    __shared__ u16 t[64][65];
    int bid = blockIdx.x, tid = threadIdx.x;
    if (bid < 8192) {
        int i = bid * 256 + tid;
        float4 f = ((const float4*)hidden)[i];
        ushort4 o = make_ushort4(f2bf(f.x), f2bf(f.y), f2bf(f.z), f2bf(f.w));
        ((ushort4*)hb)[i] = o;
        return;
    }
    int id2 = bid - 8192;                 // 1024 t4 blocks
    int bz = id2 >> 8, by = (id2 >> 4) & 15, bx = id2 & 15;
    const float* in; u16* out; int N;
    switch (bz) {
        case 0: in = w0; out = o0; N = 1024; break;
        case 1: in = w1; out = o1; N = 512;  break;
        case 2: in = w2; out = o2; N = 512;  break;
        default: in = w3; out = o3; N = 1024; break;
    }
    int kb = by * 64, nb = bx * 64;
    if (nb >= N) return;
#pragma unroll
    for (int c = 0; c < 16; ++c) {
        int id = c * 256 + tid;
        int r = id >> 6, n = id & 63;
        t[n][r] = f2bf(in[(size_t)(kb + r) * N + nb + n]);
    }
    __syncthreads();
#pragma unroll
    for (int c = 0; c < 16; ++c) {
        int id = c * 256 + tid;
        int r = id >> 6, n = id & 63;
        out[(size_t)(nb + r) * 1024 + kb + n] = t[r][n];
    }
}

// ---------------- MFMA GEMM body, BK=64, 2-phase dbuf, XOR-swizzled DMA -----
// A: [8192][K] bf16, Bt: [N][K] bf16. 128x128 tile, 256 thr = 4 waves 2x2.
// Unified T3 2-phase pipeline: prologue stages tile 0; per tile: __syncthreads
// (drains tile t's DMA, which flew during tile t-1's compute) -> issue t+1 ->
// ds_read + MFMA. LDS 64 KB -> 2 blocks/CU.
// XCD-chunked remap: hw id%8 = XCD; contiguous nid chunk per XCD so blocks
// sharing A-panels co-locate with the B panel in one 4 MiB L2.
// NOTE (R6 lesson): do NOT add sincos/RoPE to these epilogues — the extra
// register pressure on top of the live acc[4][4] spills acc to scratch
// (R6: 1.06 GB scratch writes, 300 us). RoPE stays a standalone kernel.
// MODE 0: fused QKV, N=2048. cols 0-1023 -> Qo (bias b0, unroped);
//   1024-1535 -> Ko (stride 512, bias b1); 1536-2047 -> V transposed to
//   Vto[((b*8+kvh)*64+d)*1024+s] (bias b2), packed ushort4 along s.
// MODE 1: N=1024, fp32 out Cf = acc + b0 + resid.
template<int MODE, int NBX>
__device__ __forceinline__ void gemm_body(
    const u16* __restrict__ A, const u16* __restrict__ Bt,
    const float* __restrict__ b0, const float* __restrict__ b1,
    const float* __restrict__ b2,
    const float* __restrict__ resid, float* __restrict__ Cf,
    u16* __restrict__ Qo, u16* __restrict__ Ko, u16* __restrict__ Vto,
    int N, int K)
{
    __shared__ __align__(16) u16 Asl[2][128 * 64];
    __shared__ __align__(16) u16 Bsl[2][128 * 64];
    const int tid = threadIdx.x, lane = tid & 63, w = tid >> 6;
    const int quad = lane >> 4, l16 = lane & 15;
    const int id = blockIdx.x;
    const int chunk = (NBX * 64) >> 3;                // blocks per XCD
    const int nid = (id & 7) * chunk + (id >> 3);     // id%8 -> XCD
    const int bx = nid & (NBX - 1), by = nid / NBX;
    const int bm = by * 128, bn = bx * 128;
    const int wm = (w >> 1) * 64, wn = (w & 1) * 64;

    f32x4 acc[4][4] = {};

    const int dr = lane >> 3;                       // row within 8-row band
    const int dcs = (((lane & 7) ^ dr) << 3);       // swizzled global chunk (elems)
    const u16* Ag = &A[(size_t)(bm + w * 32 + dr) * K + dcs];
    const u16* Bg = &Bt[(size_t)(bn + w * 32 + dr) * K + dcs];

    const int sw = l16 & 7;  // fragment-read swizzle

    const int NT = K >> 6;
#pragma unroll
    for (int c = 0; c < 4; ++c) {  // prologue: stage tile 0 -> buf 0
        gll16(Ag + (size_t)(c * 8) * K, &Asl[0][(w * 32 + c * 8) * 64]);
        gll16(Bg + (size_t)(c * 8) * K, &Bsl[0][(w * 32 + c * 8) * 64]);
    }
    for (int t = 0; t < NT; ++t) {
        const int cur = t & 1;
        // drains this wave's outstanding DMA (tile t, issued during the
        // previous tile's compute) + barrier -> tile t staged everywhere.
        __syncthreads();
        if (t < NT - 1) {
            const int k0 = (t + 1) * 64;
#pragma unroll
            for (int c = 0; c < 4; ++c) {
                gll16(Ag + (size_t)(c * 8) * K + k0, &Asl[cur ^ 1][(w * 32 + c * 8) * 64]);
                gll16(Bg + (size_t)(c * 8) * K + k0, &Bsl[cur ^ 1][(w * 32 + c * 8) * 64]);
            }
        }
        bf16x8 af[4][2], bfr[4][2];
#pragma unroll
        for (int i = 0; i < 4; ++i)
#pragma unroll
            for (int ks = 0; ks < 2; ++ks)
                af[i][ks] = *(const bf16x8*)&Asl[cur][(wm + i * 16 + l16) * 64 + (((ks * 4 + quad) ^ sw) << 3)];
#pragma unroll
        for (int j = 0; j < 4; ++j)
#pragma unroll
            for (int ks = 0; ks < 2; ++ks)
                bfr[j][ks] = *(const bf16x8*)&Bsl[cur][(wn + j * 16 + l16) * 64 + (((ks * 4 + quad) ^ sw) << 3)];
#pragma unroll
        for (int i = 0; i < 4; ++i)
#pragma unroll
            for (int j = 0; j < 4; ++j)
#pragma unroll
                for (int ks = 0; ks < 2; ++ks)
                    acc[i][j] = __builtin_amdgcn_mfma_f32_16x16x32_bf16(af[i][ks], bfr[j][ks], acc[i][j], 0, 0, 0);
        // no trailing barrier: next iteration's __syncthreads covers the
        // read-before-overwrite hazard (prefetch targets the other buffer).
    }

    // epilogue: C/D layout col=lane&15, row=quad*4+reg
#pragma unroll
    for (int j = 0; j < 4; ++j) {
        int col = bn + wn + j * 16 + l16;
        if (MODE == 1) {
            float bb = b0[col];
#pragma unroll
            for (int i = 0; i < 4; ++i) {
                int row0 = bm + wm + i * 16 + quad * 4;
#pragma unroll
                for (int r = 0; r < 4; ++r) {
                    size_t off = (size_t)(row0 + r) * N + col;
                    Cf[off] = acc[i][j][r] + bb + resid[off];
                }
            }
        } else if (col < 1024) {
            float bb = b0[col];
#pragma unroll
            for (int i = 0; i < 4; ++i) {
                int row0 = bm + wm + i * 16 + quad * 4;
#pragma unroll
                for (int r = 0; r < 4; ++r)
                    Qo[(size_t)(row0 + r) * 1024 + col] = f2bf(acc[i][j][r] + bb);
            }
        } else if (col < 1536) {
            int c2 = col - 1024;
            float bb = b1[c2];
#pragma unroll
            for (int i = 0; i < 4; ++i) {
                int row0 = bm + wm + i * 16 + quad * 4;
#pragma unroll
                for (int r = 0; r < 4; ++r)
                    Ko[(size_t)(row0 + r) * 512 + c2] = f2bf(acc[i][j][r] + bb);
            }
        } else {
            int c2 = col - 1536, kvh = c2 >> 6, d = c2 & 63;
            float bb = b2[c2];
#pragma unroll
            for (int i = 0; i < 4; ++i) {
                int row0 = bm + wm + i * 16 + quad * 4;
                int b = row0 >> 10, s = row0 & 1023;
                ushort4 o4;
                o4.x = f2bf(acc[i][j][0] + bb);
                o4.y = f2bf(acc[i][j][1] + bb);
                o4.z = f2bf(acc[i][j][2] + bb);
                o4.w = f2bf(acc[i][j][3] + bb);
                *(ushort4*)&Vto[(size_t)((b * 8 + kvh) * 64 + d) * 1024 + s] = o4;
            }
        }
    }
}

// Distinct kernel names so rocprof rows are unambiguous per mode.
__global__ __launch_bounds__(256) void gemm_qkv(
    const u16* __restrict__ A, const u16* __restrict__ Bt,
    const float* __restrict__ b0, const float* __restrict__ b1,
    const float* __restrict__ b2,
    u16* __restrict__ Qo, u16* __restrict__ Ko, u16* __restrict__ Vto)
{
    gemm_body<0, 16>(A, Bt, b0, b1, b2, nullptr, nullptr, Qo, Ko, Vto, 2048, 1024);
}

__global__ __launch_bounds__(256) void gemm_out(
    const u16* __restrict__ A, const u16* __restrict__ Bt,
    const float* __restrict__ b0,
    const float* __restrict__ resid, float* __restrict__ Cf)
{
    gemm_body<1, 8>(A, Bt, b0, nullptr, nullptr, resid, Cf,
                    nullptr, nullptr, nullptr, 1024, 1024);
}

// ---------------- RoPE (interleaved), in place on bf16 K, 4 pairs/thread ----
// K layout [8192][512] (kvh*64+d). thread: 4 consecutive pairs = uint4.
__global__ __launch_bounds__(256) void rope_bf16_kernel(u16* __restrict__ x)
{
    int idx = blockIdx.x * 256 + threadIdx.x;   // 524288 total
    int jg = idx & 7;                           // group of 4 pairs
    int h = (idx >> 3) & 7;                     // kvh
    int row = idx >> 6;
    float fpos = (float)(row & 1023);
    uint4 u4 = *(uint4*)&x[(size_t)row * 512 + h * 64 + jg * 8];
    unsigned* uw = &u4.x;
#pragma unroll
    for (int t = 0; t < 4; ++t) {
        int j = jg * 4 + t;
        float inv = exp2f((float)j * -0.4152410118609203f);  // 10000^(-2j/64)
        float sn, cs;
        sincosf(fpos * inv, &sn, &cs);
        unsigned u = uw[t];
        float x1 = bf2f((u16)(u & 0xffff)), x2 = bf2f((u16)(u >> 16));
        float y1 = x1 * cs - x2 * sn, y2 = x1 * sn + x2 * cs;
        uw[t] = (unsigned)f2bf(y1) | ((unsigned)f2bf(y2) << 16);
    }
    *(uint4*)&x[(size_t)row * 512 + h * 64 + jg * 8] = u4;
}

// ---------------- MFMA flash attention: 128 q/block, fused Q-RoPE -----------
// R4-proven version (54.1 us): Ps LDS bounce kept — R5 showed removing it
// regresses (the compiler hides the Ps chain; split b64 V-reads cost more).
// Q: [8192][1024] bf16 (h*64+d, UNroped). K: [8192][512] (kvh*64+d, roped).
// Vt: [(b*8+kvh)*64+d][1024 keys] bf16 (pre-transposed).
// T3 2-phase: double-buffered Ks/Vts, one __syncthreads per tile (its vmcnt(0)
// drain is exactly tile kt's DMA, in flight during kt-1's compute).
// Ps [64][40]: PV is q-group-serial with V fragments cached in regs; each wave
// time-shares a 16-row Ps band (in-wave LDS ordering, no barrier).
// LDS 37.9 KB -> 4 blocks/CU; grid 1024 = 256 CU x 4 fully co-resident.
// XCD-chunked swizzle: each batch b (K+V 2.1 MB) pinned to one XCD L2
// (verified R4: FETCH 74 -> 16.5 MB).
__global__ __launch_bounds__(256, 4) void attn_mfma(
    const u16* __restrict__ Q, const u16* __restrict__ K,
    const u16* __restrict__ Vt, u16* __restrict__ O)
{
    __shared__ __align__(16) u16 Ks[2][64 * 64];   // [buf][key][d], swizzled chunks
    __shared__ __align__(16) u16 Vts[2][64 * 64];  // [buf][d][key], swizzled chunks
    __shared__ __align__(16) u16 Ps[64][40];       // [wave 16-row band][32 keys + pad]

    const int tid = threadIdx.x, lane = tid & 63, w = tid >> 6;
    const int quad = lane >> 4, l16 = lane & 15;
    const int id = blockIdx.x;
    const int nid = (id & 7) * 128 + (id >> 3);    // XCD-chunked (id%8 -> XCD)
    const int qt = nid & 7, h = (nid >> 3) & 15, b = nid >> 7;
    const int kvh = h >> 1;
    const size_t qrow0 = (size_t)b * 1024 + qt * 128;
    const size_t krow0 = (size_t)b * 1024;
    const u16* Vg = Vt + (size_t)((b * 8 + kvh) * 64) * 1024;

    // DMA staging: per wave 16 rows each of K,V^T; 2 calls of 8 rows each.
    const int dr = lane >> 3;                    // row in 8-row band
    const int dcs = (((lane & 7) ^ dr) << 3);    // swizzled global chunk (elems)
    const u16* Kg0 = &K[(krow0 + w * 16 + dr) * 512 + kvh * 64 + dcs];
    const u16* Vg0 = &Vg[(size_t)(w * 16 + dr) * 1024 + dcs];
    const int sw = l16 & 7;
    const float C1 = 0.18033688011112043f;  // 0.125 * log2(e), folded into Q

    // prologue: stage tile 0 into buffer 0 (overlaps Q-RoPE prep below)
#pragma unroll
    for (int c = 0; c < 2; ++c) {
        gll16(Kg0 + (size_t)(c * 8) * 512, &Ks[0][(w * 16 + c * 8) * 64]);
        gll16(Vg0 + (size_t)(c * 8) * 1024, &Vts[0][(w * 16 + c * 8) * 64]);
    }

    // Q fragments with RoPE (and softmax scale C1) applied in-register.
    bf16x8 qf[2][2];
#pragma unroll
    for (int qg = 0; qg < 2; ++qg) {
        int qrow = w * 32 + qg * 16 + l16;
        float fpos = (float)(qt * 128 + qrow);
#pragma unroll
        for (int ks = 0; ks < 2; ++ks) {
            uint4 qraw = *(const uint4*)&Q[(qrow0 + qrow) * 1024 + h * 64 + ks * 32 + quad * 8];
            unsigned o_[4];
#pragma unroll
            for (int t = 0; t < 4; ++t) {
                int j = ks * 16 + quad * 4 + t;
                float inv = exp2f((float)j * -0.4152410118609203f);
                float sn_, cs_;
                sincosf(fpos * inv, &sn_, &cs_);
                cs_ *= C1; sn_ *= C1;            // fold softmax scale into Q
                unsigned u = (&qraw.x)[t];
                float x1 = bf2f((u16)(u & 0xffff)), x2 = bf2f((u16)(u >> 16));
                float y1 = x1 * cs_ - x2 * sn_, y2 = x1 * sn_ + x2 * cs_;
                o_[t] = (unsigned)f2bf(y1) | ((unsigned)f2bf(y2) << 16);
            }
            qf[qg][ks] = __builtin_bit_cast(bf16x8, make_uint4(o_[0], o_[1], o_[2], o_[3]));
        }
    }

    f32x4 acc_o[2][4] = {};
    f32x4 lsum[2] = {};  // ones-MFMA row-sum accumulator (all regs equal at end)
    const bf16x8 ones = __builtin_bit_cast(bf16x8,
        make_uint4(0x3F803F80u, 0x3F803F80u, 0x3F803F80u, 0x3F803F80u));

    for (int kt = 0; kt < 16; ++kt) {
        const int cur = kt & 1;
        // drains this wave's outstanding DMA (tile kt, in flight during the
        // previous tile's compute) + barrier -> tile kt staged everywhere.
        __syncthreads();

        // prefetch tile kt+1 into the other buffer; its last reader was
        // compute(kt-1), which precedes this barrier for all waves.
        if (kt < 15) {
#pragma unroll
            for (int c = 0; c < 2; ++c) {
                gll16(Kg0 + (size_t)((kt + 1) * 64 + c * 8) * 512,
                      &Ks[cur ^ 1][(w * 16 + c * 8) * 64]);
                gll16(Vg0 + (size_t)(c * 8) * 1024 + (kt + 1) * 64,
                      &Vts[cur ^ 1][(w * 16 + c * 8) * 64]);
            }
        }

        // S^T = K . Q^T : s[qg][nt] holds keys nt*16+quad*4+(0..3) for q-group qg
        f32x4 s[2][4] = {};
        __builtin_amdgcn_s_setprio(1);
#pragma unroll
        for (int ks = 0; ks < 2; ++ks) {
#pragma unroll
            for (int nt = 0; nt < 4; ++nt) {
                bf16x8 ak = *(const bf16x8*)&Ks[cur][(nt * 16 + l16) * 64 + (((ks * 4 + quad) ^ sw) << 3)];
                s[0][nt] = __builtin_amdgcn_mfma_f32_16x16x32_bf16(ak, qf[0][ks], s[0][nt], 0, 0, 0);
                s[1][nt] = __builtin_amdgcn_mfma_f32_16x16x32_bf16(ak, qf[1][ks], s[1][nt], 0, 0, 0);
            }
        }
        __builtin_amdgcn_s_setprio(0);

        // per key-chunk kc (keys kc*32..+31): softmax -> Ps band, then PV MFMA.
        // Ps band is wave-private AND time-shared across (kc, qg): in-wave LDS
        // ordering guarantees qg0's read completes before qg1's overwrite.
#pragma unroll
        for (int kc = 0; kc < 2; ++kc) {
            bf16x8 av[4];  // V fragments cached: shared by both q-groups
#pragma unroll
            for (int nt = 0; nt < 4; ++nt)
                av[nt] = *(const bf16x8*)&Vts[cur][(nt * 16 + l16) * 64 + (((kc * 4 + quad) ^ sw) << 3)];
#pragma unroll
            for (int qg = 0; qg < 2; ++qg) {
#pragma unroll
                for (int ntl = 0; ntl < 2; ++ntl) {
                    int nt = kc * 2 + ntl;
                    float p0 = __builtin_amdgcn_exp2f(s[qg][nt][0]);
                    float p1 = __builtin_amdgcn_exp2f(s[qg][nt][1]);
                    unsigned pk0 = __builtin_amdgcn_perm(
                        __builtin_bit_cast(unsigned, p1),
                        __builtin_bit_cast(unsigned, p0), 0x07060302u);
                    float p2 = __builtin_amdgcn_exp2f(s[qg][nt][2]);
                    float p3 = __builtin_amdgcn_exp2f(s[qg][nt][3]);
                    unsigned pk1 = __builtin_amdgcn_perm(
                        __builtin_bit_cast(unsigned, p3),
                        __builtin_bit_cast(unsigned, p2), 0x07060302u);
                    *(uint2*)&Ps[w * 16 + l16][ntl * 16 + quad * 4] = make_uint2(pk0, pk1);
                }
                bf16x8 bp = *(const bf16x8*)&Ps[w * 16 + l16][quad * 8];
                __builtin_amdgcn_s_setprio(1);
                // l_i = P . 1 via ones-MFMA (sums the exact bf16 P used by PV)
                lsum[qg] = __builtin_amdgcn_mfma_f32_16x16x32_bf16(ones, bp, lsum[qg], 0, 0, 0);
                // O^T += V^T(chunk kc) . P^T(chunk kc)
#pragma unroll
                for (int nt = 0; nt < 4; ++nt)
                    acc_o[qg][nt] = __builtin_amdgcn_mfma_f32_16x16x32_bf16(av[nt], bp, acc_o[qg][nt], 0, 0, 0);
                __builtin_amdgcn_s_setprio(0);
            }
        }
        // no trailing barrier: next iteration's __syncthreads covers the
        // read-before-overwrite hazard (prefetch targets the other buffer).
    }

    // epilogue: lsum already holds full row sums (all lanes/regs for q=l16)
#pragma unroll
    for (int qg = 0; qg < 2; ++qg) {
        float rl = 1.0f / lsum[qg][0];
        size_t orow = (qrow0 + w * 32 + qg * 16 + l16) * 1024 + h * 64;
#pragma unroll
        for (int nt = 0; nt < 4; ++nt) {
            ushort4 o4;
            o4.x = f2bf(acc_o[qg][nt][0] * rl);
            o4.y = f2bf(acc_o[qg][nt][1] * rl);
            o4.z = f2bf(acc_o[qg][nt][2] * rl);
            o4.w = f2bf(acc_o[qg][nt][3] * rl);
            *(ushort4*)&O[orow + nt * 16 + quad * 4] = o4;
        }
    }
}

// ---------------- LayerNorm in place on [8192][1024] fp32 ----------------
__global__ __launch_bounds__(256) void ln_kernel(float* __restrict__ io,
    const float* __restrict__ gamma, const float* __restrict__ beta)
{
    int row = blockIdx.x;
    int tid = threadIdx.x;
    float* p = io + (size_t)row * 1024;
    float4 x = *reinterpret_cast<const float4*>(&p[tid << 2]);
    float s = x.x + x.y + x.z + x.w;
    float ss = fmaf(x.x, x.x, fmaf(x.y, x.y, fmaf(x.z, x.z, x.w * x.w)));
#pragma unroll
    for (int off = 32; off > 0; off >>= 1) {
        s  += __shfl_down(s, off);
        ss += __shfl_down(ss, off);
    }
    __shared__ float rs[4], rss[4];
    int lane = tid & 63, wid = tid >> 6;
    if (lane == 0) { rs[wid] = s; rss[wid] = ss; }
    __syncthreads();
    float S = rs[0] + rs[1] + rs[2] + rs[3];
    float SS = rss[0] + rss[1] + rss[2] + rss[3];
    float mu = S * (1.0f / 1024.0f);
    float var = SS * (1.0f / 1024.0f) - mu * mu;
    float rstd = rsqrtf(var + 1e-12f);
    float4 g = *reinterpret_cast<const float4*>(&gamma[tid << 2]);
    float4 be = *reinterpret_cast<const float4*>(&beta[tid << 2]);
    float4 o;
    o.x = (x.x - mu) * rstd * g.x + be.x;
    o.y = (x.y - mu) * rstd * g.y + be.y;
    o.z = (x.z - mu) * rstd * g.z + be.z;
    o.w = (x.w - mu) * rstd * g.w + be.w;
    *reinterpret_cast<float4*>(&p[tid << 2]) = o;
}

// ---------------- launch ----------------
extern "C" void kernel_launch(void* const* d_in, const int* in_sizes, int n_in,
                              void* d_out, int out_size, void* d_ws, size_t ws_size,
                              hipStream_t stream)
{
    (void)in_sizes; (void)n_in; (void)out_size; (void)ws_size;
    const float* hidden = (const float*)d_in[0];
    const float* Wq = (const float*)d_in[1];
    const float* bq = (const float*)d_in[2];
    const float* Wk = (const float*)d_in[3];
    const float* bk = (const float*)d_in[4];
    const float* Wv = (const float*)d_in[5];
    const float* bv = (const float*)d_in[6];
    const float* Wo = (const float*)d_in[7];
    const float* bo = (const float*)d_in[8];
    const float* g  = (const float*)d_in[9];
    const float* be = (const float*)d_in[10];
    float* out = (float*)d_out;

    // workspace layout (Wqt/Wkt/Wvt contiguous => one [2048][1024] B^T matrix)
    u16* hb  = (u16*)d_ws;                       // [8192][1024] bf16 hidden
    u16* Wqt = hb  + (size_t)8192 * 1024;        // [1024][1024] Wq^T
    u16* Wkt = Wqt + (size_t)1024 * 1024;        // [512][1024]  Wk^T
    u16* Wvt = Wkt + (size_t)512 * 1024;         // [512][1024]  Wv^T
    u16* Wot = Wvt + (size_t)512 * 1024;         // [1024][1024] Wo^T
    u16* Qb  = Wot + (size_t)1024 * 1024;        // [8192][1024] Q (then attn out)
    u16* Kb  = Qb  + (size_t)8192 * 1024;        // [8192][512]  K
    u16* Vtb = Kb  + (size_t)8192 * 512;         // [4096][1024] V^T per (b,kvh)
    // total ~66 MB

    cvt_all_kernel<<<9216, 256, 0, stream>>>(hidden, hb, Wq, Wk, Wv, Wo,
                                             Wqt, Wkt, Wvt, Wot);

    // fused QKV: N=2048 (Bt = [Wq^T;Wk^T;Wv^T]), writes Qb (unroped), Kb, Vtb
    gemm_qkv<<<dim3(1024), 256, 0, stream>>>(hb, Wqt, bq, bk, bv, Qb, Kb, Vtb);

    // RoPE on K only (Q roped inside attn)
    rope_bf16_kernel<<<2048, 256, 0, stream>>>(Kb);

    attn_mfma<<<dim3(1024), 256, 0, stream>>>(Qb, Kb, Vtb, Qb);

    // out-proj: fp32 out + bias + resid, 2-phase pipelined
    gemm_out<<<dim3(512), 256, 0, stream>>>(Qb, Wot, bo, hidden, out);

    ln_kernel<<<8192, 256, 0, stream>>>(out, g, be);
}

// Round 9
// 233.745 us; speedup vs baseline: 2.0137x; 1.0016x over previous
//
#include <hip/hip_runtime.h>
#include <math.h>
#include <stdint.h>

typedef unsigned short u16;
typedef __bf16 bf16x8 __attribute__((ext_vector_type(8)));
typedef float f32x4 __attribute__((ext_vector_type(4)));

typedef const __attribute__((address_space(1))) void gv_t;
typedef __attribute__((address_space(3))) void lv_t;

__device__ __forceinline__ u16 f2bf(float f) {
    unsigned u = __builtin_bit_cast(unsigned, f);
    return (u16)((u + 0x7FFFu + ((u >> 16) & 1u)) >> 16);
}
__device__ __forceinline__ float bf2f(u16 h) {
    return __builtin_bit_cast(float, (unsigned)h << 16);
}
// async global->LDS, 16B per lane; LDS dest = wave-uniform base + lane*16
__device__ __forceinline__ void gll16(const void* g, void* l) {
    __builtin_amdgcn_global_load_lds((gv_t*)(uintptr_t)g,
                                     (lv_t*)(unsigned)(uintptr_t)l, 16, 0, 0);
}

// ---------------- fused conversions: hidden fp32->bf16 + 4 weight transposes ----
// blocks [0,8192): hidden cvt (float4 per lane). blocks [8192,9216): weight
// fp32 [1024][N] -> bf16 [N][1024] transpose via 64x64 LDS tile.
__global__ __launch_bounds__(256) void cvt_all_kernel(
    const float* __restrict__ hidden, u16* __restrict__ hb,
    const float* __restrict__ w0, const float* __restrict__ w1,
    const float* __restrict__ w2, const float* __restrict__ w3,
    u16* __restrict__ o0, u16* __restrict__ o1,
    u16* __restrict__ o2, u16* __restrict__ o3)
{
    __shared__ u16 t[64][65];
    int bid = blockIdx.x, tid = threadIdx.x;
    if (bid < 8192) {
        int i = bid * 256 + tid;
        float4 f = ((const float4*)hidden)[i];
        ushort4 o = make_ushort4(f2bf(f.x), f2bf(f.y), f2bf(f.z), f2bf(f.w));
        ((ushort4*)hb)[i] = o;
        return;
    }
    int id2 = bid - 8192;                 // 1024 t4 blocks
    int bz = id2 >> 8, by = (id2 >> 4) & 15, bx = id2 & 15;
    const float* in; u16* out; int N;
    switch (bz) {
        case 0: in = w0; out = o0; N = 1024; break;
        case 1: in = w1; out = o1; N = 512;  break;
        case 2: in = w2; out = o2; N = 512;  break;
        default: in = w3; out = o3; N = 1024; break;
    }
    int kb = by * 64, nb = bx * 64;
    if (nb >= N) return;
#pragma unroll
    for (int c = 0; c < 16; ++c) {
        int id = c * 256 + tid;
        int r = id >> 6, n = id & 63;
        t[n][r] = f2bf(in[(size_t)(kb + r) * N + nb + n]);
    }
    __syncthreads();
#pragma unroll
    for (int c = 0; c < 16; ++c) {
        int id = c * 256 + tid;
        int r = id >> 6, n = id & 63;
        out[(size_t)(nb + r) * 1024 + kb + n] = t[r][n];
    }
}

// ---------------- 256x256 fused-QKV GEMM: 8 waves, BK=64, 2-phase dbuf -------
// A [8192][1024] bf16, Bt [2048][1024] bf16. Grid 256 = 1 block/CU, 0 tail.
// Rationale (R7): the 128^2 2-phase sits at the documented ~750-900 TF
// structure ceiling; 256^2 doubles MFMA per barrier (64/wave) at the SAME
// per-wave staging cost (8 gll16) and reuses B-fragments across 8 m-frags.
// Sync semantics identical to the proven R4 2-phase: one __syncthreads per
// K-tile (its vmcnt(0) drain is exactly tile t's DMA, issued during t-1's
// compute); prefetch targets the other buffer; no trailing barrier.
// R8 lesson: dynamic LDS + hipFuncSetAttribute inside kernel_launch broke
// the harness (graph capture). STATIC 128 KB __shared__ instead (gfx950 has
// 160 KiB/CU; m201 precedent compiles 128 KiB plain-HIP).
// cols 0-1023 -> Qo (bias b0); 1024-1535 -> Ko (stride 512, bias b1);
// 1536-2047 -> V transposed to Vto[((b*8+kvh)*64+d)*1024+s] (bias b2).
__global__ __launch_bounds__(512, 2) void gemm_qkv(
    const u16* __restrict__ A, const u16* __restrict__ Bt,
    const float* __restrict__ b0, const float* __restrict__ b1,
    const float* __restrict__ b2,
    u16* __restrict__ Qo, u16* __restrict__ Ko, u16* __restrict__ Vto)
{
    __shared__ __align__(16) u16 Asl[2][256 * 64];   // 64 KB
    __shared__ __align__(16) u16 Bsl[2][256 * 64];   // 64 KB
    const int tid = threadIdx.x, lane = tid & 63, w = tid >> 6;  // w 0..7
    const int quad = lane >> 4, l16 = lane & 15;
    const int id = blockIdx.x;
    const int nid = (id & 7) * 32 + (id >> 3);    // XCD-chunked (id%8 -> XCD)
    const int bx = nid & 7, by = nid >> 3;
    const int bm = by * 256, bn = bx * 256;
    const int wm = (w >> 2) * 128, wn = (w & 3) * 64;   // 2M x 4N waves

    f32x4 acc[8][4] = {};   // 128 VGPR

    const int dr = lane >> 3;                       // row within 8-row band
    const int dcs = (((lane & 7) ^ dr) << 3);       // swizzled global chunk (elems)
    const u16* Ag = &A[(size_t)(bm + w * 32 + dr) * 1024 + dcs];
    const u16* Bg = &Bt[(size_t)(bn + w * 32 + dr) * 1024 + dcs];
    const int sw = l16 & 7;                         // fragment-read swizzle

#pragma unroll
    for (int c = 0; c < 4; ++c) {   // prologue: stage tile 0 -> buf 0
        gll16(Ag + (size_t)(c * 8) * 1024, &Asl[0][(w * 32 + c * 8) * 64]);
        gll16(Bg + (size_t)(c * 8) * 1024, &Bsl[0][(w * 32 + c * 8) * 64]);
    }
    for (int t = 0; t < 16; ++t) {
        const int cur = t & 1;
        // drains this wave's outstanding DMA (tile t, issued during the
        // previous tile's compute) + barrier -> tile t staged everywhere.
        __syncthreads();
        if (t < 15) {
            const int k0 = (t + 1) * 64;
#pragma unroll
            for (int c = 0; c < 4; ++c) {
                gll16(Ag + (size_t)(c * 8) * 1024 + k0, &Asl[cur ^ 1][(w * 32 + c * 8) * 64]);
                gll16(Bg + (size_t)(c * 8) * 1024 + k0, &Bsl[cur ^ 1][(w * 32 + c * 8) * 64]);
            }
        }
        bf16x8 bfr[4][2];
#pragma unroll
        for (int j = 0; j < 4; ++j)
#pragma unroll
            for (int ks = 0; ks < 2; ++ks)
                bfr[j][ks] = *(const bf16x8*)&Bsl[cur][(wn + j * 16 + l16) * 64 + (((ks * 4 + quad) ^ sw) << 3)];
#pragma unroll
        for (int i = 0; i < 8; ++i) {
            bf16x8 af0 = *(const bf16x8*)&Asl[cur][(wm + i * 16 + l16) * 64 + ((quad ^ sw) << 3)];
            bf16x8 af1 = *(const bf16x8*)&Asl[cur][(wm + i * 16 + l16) * 64 + (((4 + quad) ^ sw) << 3)];
#pragma unroll
            for (int j = 0; j < 4; ++j) {
                acc[i][j] = __builtin_amdgcn_mfma_f32_16x16x32_bf16(af0, bfr[j][0], acc[i][j], 0, 0, 0);
                acc[i][j] = __builtin_amdgcn_mfma_f32_16x16x32_bf16(af1, bfr[j][1], acc[i][j], 0, 0, 0);
            }
        }
        // no trailing barrier: next iteration's __syncthreads covers the
        // read-before-overwrite hazard (prefetch targets the other buffer).
    }

    // epilogue: C/D layout col=lane&15, row=quad*4+reg. 256-col block ranges
    // never straddle the 1024/1536 boundaries (all multiples of 256).
#pragma unroll
    for (int j = 0; j < 4; ++j) {
        int col = bn + wn + j * 16 + l16;
        if (col < 1024) {
            float bb = b0[col];
#pragma unroll
            for (int i = 0; i < 8; ++i) {
                int row0 = bm + wm + i * 16 + quad * 4;
#pragma unroll
                for (int r = 0; r < 4; ++r)
                    Qo[(size_t)(row0 + r) * 1024 + col] = f2bf(acc[i][j][r] + bb);
            }
        } else if (col < 1536) {
            int c2 = col - 1024;
            float bb = b1[c2];
#pragma unroll
            for (int i = 0; i < 8; ++i) {
                int row0 = bm + wm + i * 16 + quad * 4;
#pragma unroll
                for (int r = 0; r < 4; ++r)
                    Ko[(size_t)(row0 + r) * 512 + c2] = f2bf(acc[i][j][r] + bb);
            }
        } else {
            int c2 = col - 1536, kvh = c2 >> 6, d = c2 & 63;
            float bb = b2[c2];
#pragma unroll
            for (int i = 0; i < 8; ++i) {
                int row0 = bm + wm + i * 16 + quad * 4;
                int b = row0 >> 10, s = row0 & 1023;
                ushort4 o4;
                o4.x = f2bf(acc[i][j][0] + bb);
                o4.y = f2bf(acc[i][j][1] + bb);
                o4.z = f2bf(acc[i][j][2] + bb);
                o4.w = f2bf(acc[i][j][3] + bb);
                *(ushort4*)&Vto[(size_t)((b * 8 + kvh) * 64 + d) * 1024 + s] = o4;
            }
        }
    }
}

// ---------------- out-proj GEMM (proven R3 2-phase, 128x128, unchanged) -----
// N=1024, fp32 out Cf = acc + b0 + resid. Grid 512 = 2 blocks/CU.
// NOTE (R6 lesson): no sincos/extra math in this epilogue — spills acc.
__global__ __launch_bounds__(256) void gemm_out(
    const u16* __restrict__ A, const u16* __restrict__ Bt,
    const float* __restrict__ b0,
    const float* __restrict__ resid, float* __restrict__ Cf)
{
    __shared__ __align__(16) u16 Asl[2][128 * 64];
    __shared__ __align__(16) u16 Bsl[2][128 * 64];
    const int tid = threadIdx.x, lane = tid & 63, w = tid >> 6;
    const int quad = lane >> 4, l16 = lane & 15;
    const int id = blockIdx.x;
    const int nid = (id & 7) * 64 + (id >> 3);     // XCD-chunked, 512 blocks
    const int bx = nid & 7, by = nid >> 3;
    const int bm = by * 128, bn = bx * 128;
    const int wm = (w >> 1) * 64, wn = (w & 1) * 64;
    const int K = 1024, N = 1024;

    f32x4 acc[4][4] = {};

    const int dr = lane >> 3;
    const int dcs = (((lane & 7) ^ dr) << 3);
    const u16* Ag = &A[(size_t)(bm + w * 32 + dr) * K + dcs];
    const u16* Bg = &Bt[(size_t)(bn + w * 32 + dr) * K + dcs];
    const int sw = l16 & 7;

#pragma unroll
    for (int c = 0; c < 4; ++c) {
        gll16(Ag + (size_t)(c * 8) * K, &Asl[0][(w * 32 + c * 8) * 64]);
        gll16(Bg + (size_t)(c * 8) * K, &Bsl[0][(w * 32 + c * 8) * 64]);
    }
    for (int t = 0; t < 16; ++t) {
        const int cur = t & 1;
        __syncthreads();
        if (t < 15) {
            const int k0 = (t + 1) * 64;
#pragma unroll
            for (int c = 0; c < 4; ++c) {
                gll16(Ag + (size_t)(c * 8) * K + k0, &Asl[cur ^ 1][(w * 32 + c * 8) * 64]);
                gll16(Bg + (size_t)(c * 8) * K + k0, &Bsl[cur ^ 1][(w * 32 + c * 8) * 64]);
            }
        }
        bf16x8 af[4][2], bfr[4][2];
#pragma unroll
        for (int i = 0; i < 4; ++i)
#pragma unroll
            for (int ks = 0; ks < 2; ++ks)
                af[i][ks] = *(const bf16x8*)&Asl[cur][(wm + i * 16 + l16) * 64 + (((ks * 4 + quad) ^ sw) << 3)];
#pragma unroll
        for (int j = 0; j < 4; ++j)
#pragma unroll
            for (int ks = 0; ks < 2; ++ks)
                bfr[j][ks] = *(const bf16x8*)&Bsl[cur][(wn + j * 16 + l16) * 64 + (((ks * 4 + quad) ^ sw) << 3)];
#pragma unroll
        for (int i = 0; i < 4; ++i)
#pragma unroll
            for (int j = 0; j < 4; ++j)
#pragma unroll
                for (int ks = 0; ks < 2; ++ks)
                    acc[i][j] = __builtin_amdgcn_mfma_f32_16x16x32_bf16(af[i][ks], bfr[j][ks], acc[i][j], 0, 0, 0);
    }

#pragma unroll
    for (int j = 0; j < 4; ++j) {
        int col = bn + wn + j * 16 + l16;
        float bb = b0[col];
#pragma unroll
        for (int i = 0; i < 4; ++i) {
            int row0 = bm + wm + i * 16 + quad * 4;
#pragma unroll
            for (int r = 0; r < 4; ++r) {
                size_t off = (size_t)(row0 + r) * N + col;
                Cf[off] = acc[i][j][r] + bb + resid[off];
            }
        }
    }
}

// ---------------- RoPE (interleaved), in place on bf16 K, 4 pairs/thread ----
// K layout [8192][512] (kvh*64+d). thread: 4 consecutive pairs = uint4.
__global__ __launch_bounds__(256) void rope_bf16_kernel(u16* __restrict__ x)
{
    int idx = blockIdx.x * 256 + threadIdx.x;   // 524288 total
    int jg = idx & 7;                           // group of 4 pairs
    int h = (idx >> 3) & 7;                     // kvh
    int row = idx >> 6;
    float fpos = (float)(row & 1023);
    uint4 u4 = *(uint4*)&x[(size_t)row * 512 + h * 64 + jg * 8];
    unsigned* uw = &u4.x;
#pragma unroll
    for (int t = 0; t < 4; ++t) {
        int j = jg * 4 + t;
        float inv = exp2f((float)j * -0.4152410118609203f);  // 10000^(-2j/64)
        float sn, cs;
        sincosf(fpos * inv, &sn, &cs);
        unsigned u = uw[t];
        float x1 = bf2f((u16)(u & 0xffff)), x2 = bf2f((u16)(u >> 16));
        float y1 = x1 * cs - x2 * sn, y2 = x1 * sn + x2 * cs;
        uw[t] = (unsigned)f2bf(y1) | ((unsigned)f2bf(y2) << 16);
    }
    *(uint4*)&x[(size_t)row * 512 + h * 64 + jg * 8] = u4;
}

// ---------------- MFMA flash attention: 128 q/block, fused Q-RoPE -----------
// R4-proven version (53-54 us), unchanged.
__global__ __launch_bounds__(256, 4) void attn_mfma(
    const u16* __restrict__ Q, const u16* __restrict__ K,
    const u16* __restrict__ Vt, u16* __restrict__ O)
{
    __shared__ __align__(16) u16 Ks[2][64 * 64];   // [buf][key][d], swizzled chunks
    __shared__ __align__(16) u16 Vts[2][64 * 64];  // [buf][d][key], swizzled chunks
    __shared__ __align__(16) u16 Ps[64][40];       // [wave 16-row band][32 keys + pad]

    const int tid = threadIdx.x, lane = tid & 63, w = tid >> 6;
    const int quad = lane >> 4, l16 = lane & 15;
    const int id = blockIdx.x;
    const int nid = (id & 7) * 128 + (id >> 3);    // XCD-chunked (id%8 -> XCD)
    const int qt = nid & 7, h = (nid >> 3) & 15, b = nid >> 7;
    const int kvh = h >> 1;
    const size_t qrow0 = (size_t)b * 1024 + qt * 128;
    const size_t krow0 = (size_t)b * 1024;
    const u16* Vg = Vt + (size_t)((b * 8 + kvh) * 64) * 1024;

    const int dr = lane >> 3;
    const int dcs = (((lane & 7) ^ dr) << 3);
    const u16* Kg0 = &K[(krow0 + w * 16 + dr) * 512 + kvh * 64 + dcs];
    const u16* Vg0 = &Vg[(size_t)(w * 16 + dr) * 1024 + dcs];
    const int sw = l16 & 7;
    const float C1 = 0.18033688011112043f;  // 0.125 * log2(e), folded into Q

#pragma unroll
    for (int c = 0; c < 2; ++c) {
        gll16(Kg0 + (size_t)(c * 8) * 512, &Ks[0][(w * 16 + c * 8) * 64]);
        gll16(Vg0 + (size_t)(c * 8) * 1024, &Vts[0][(w * 16 + c * 8) * 64]);
    }

    bf16x8 qf[2][2];
#pragma unroll
    for (int qg = 0; qg < 2; ++qg) {
        int qrow = w * 32 + qg * 16 + l16;
        float fpos = (float)(qt * 128 + qrow);
#pragma unroll
        for (int ks = 0; ks < 2; ++ks) {
            uint4 qraw = *(const uint4*)&Q[(qrow0 + qrow) * 1024 + h * 64 + ks * 32 + quad * 8];
            unsigned o_[4];
#pragma unroll
            for (int t = 0; t < 4; ++t) {
                int j = ks * 16 + quad * 4 + t;
                float inv = exp2f((float)j * -0.4152410118609203f);
                float sn_, cs_;
                sincosf(fpos * inv, &sn_, &cs_);
                cs_ *= C1; sn_ *= C1;            // fold softmax scale into Q
                unsigned u = (&qraw.x)[t];
                float x1 = bf2f((u16)(u & 0xffff)), x2 = bf2f((u16)(u >> 16));
                float y1 = x1 * cs_ - x2 * sn_, y2 = x1 * sn_ + x2 * cs_;
                o_[t] = (unsigned)f2bf(y1) | ((unsigned)f2bf(y2) << 16);
            }
            qf[qg][ks] = __builtin_bit_cast(bf16x8, make_uint4(o_[0], o_[1], o_[2], o_[3]));
        }
    }

    f32x4 acc_o[2][4] = {};
    f32x4 lsum[2] = {};  // ones-MFMA row-sum accumulator
    const bf16x8 ones = __builtin_bit_cast(bf16x8,
        make_uint4(0x3F803F80u, 0x3F803F80u, 0x3F803F80u, 0x3F803F80u));

    for (int kt = 0; kt < 16; ++kt) {
        const int cur = kt & 1;
        __syncthreads();

        if (kt < 15) {
#pragma unroll
            for (int c = 0; c < 2; ++c) {
                gll16(Kg0 + (size_t)((kt + 1) * 64 + c * 8) * 512,
                      &Ks[cur ^ 1][(w * 16 + c * 8) * 64]);
                gll16(Vg0 + (size_t)(c * 8) * 1024 + (kt + 1) * 64,
                      &Vts[cur ^ 1][(w * 16 + c * 8) * 64]);
            }
        }

        f32x4 s[2][4] = {};
        __builtin_amdgcn_s_setprio(1);
#pragma unroll
        for (int ks = 0; ks < 2; ++ks) {
#pragma unroll
            for (int nt = 0; nt < 4; ++nt) {
                bf16x8 ak = *(const bf16x8*)&Ks[cur][(nt * 16 + l16) * 64 + (((ks * 4 + quad) ^ sw) << 3)];
                s[0][nt] = __builtin_amdgcn_mfma_f32_16x16x32_bf16(ak, qf[0][ks], s[0][nt], 0, 0, 0);
                s[1][nt] = __builtin_amdgcn_mfma_f32_16x16x32_bf16(ak, qf[1][ks], s[1][nt], 0, 0, 0);
            }
        }
        __builtin_amdgcn_s_setprio(0);

#pragma unroll
        for (int kc = 0; kc < 2; ++kc) {
            bf16x8 av[4];  // V fragments cached: shared by both q-groups
#pragma unroll
            for (int nt = 0; nt < 4; ++nt)
                av[nt] = *(const bf16x8*)&Vts[cur][(nt * 16 + l16) * 64 + (((kc * 4 + quad) ^ sw) << 3)];
#pragma unroll
            for (int qg = 0; qg < 2; ++qg) {
#pragma unroll
                for (int ntl = 0; ntl < 2; ++ntl) {
                    int nt = kc * 2 + ntl;
                    float p0 = __builtin_amdgcn_exp2f(s[qg][nt][0]);
                    float p1 = __builtin_amdgcn_exp2f(s[qg][nt][1]);
                    unsigned pk0 = __builtin_amdgcn_perm(
                        __builtin_bit_cast(unsigned, p1),
                        __builtin_bit_cast(unsigned, p0), 0x07060302u);
                    float p2 = __builtin_amdgcn_exp2f(s[qg][nt][2]);
                    float p3 = __builtin_amdgcn_exp2f(s[qg][nt][3]);
                    unsigned pk1 = __builtin_amdgcn_perm(
                        __builtin_bit_cast(unsigned, p3),
                        __builtin_bit_cast(unsigned, p2), 0x07060302u);
                    *(uint2*)&Ps[w * 16 + l16][ntl * 16 + quad * 4] = make_uint2(pk0, pk1);
                }
                bf16x8 bp = *(const bf16x8*)&Ps[w * 16 + l16][quad * 8];
                __builtin_amdgcn_s_setprio(1);
                lsum[qg] = __builtin_amdgcn_mfma_f32_16x16x32_bf16(ones, bp, lsum[qg], 0, 0, 0);
#pragma unroll
                for (int nt = 0; nt < 4; ++nt)
                    acc_o[qg][nt] = __builtin_amdgcn_mfma_f32_16x16x32_bf16(av[nt], bp, acc_o[qg][nt], 0, 0, 0);
                __builtin_amdgcn_s_setprio(0);
            }
        }
    }

#pragma unroll
    for (int qg = 0; qg < 2; ++qg) {
        float rl = 1.0f / lsum[qg][0];
        size_t orow = (qrow0 + w * 32 + qg * 16 + l16) * 1024 + h * 64;
#pragma unroll
        for (int nt = 0; nt < 4; ++nt) {
            ushort4 o4;
            o4.x = f2bf(acc_o[qg][nt][0] * rl);
            o4.y = f2bf(acc_o[qg][nt][1] * rl);
            o4.z = f2bf(acc_o[qg][nt][2] * rl);
            o4.w = f2bf(acc_o[qg][nt][3] * rl);
            *(ushort4*)&O[orow + nt * 16 + quad * 4] = o4;
        }
    }
}

// ---------------- LayerNorm in place on [8192][1024] fp32 ----------------
__global__ __launch_bounds__(256) void ln_kernel(float* __restrict__ io,
    const float* __restrict__ gamma, const float* __restrict__ beta)
{
    int row = blockIdx.x;
    int tid = threadIdx.x;
    float* p = io + (size_t)row * 1024;
    float4 x = *reinterpret_cast<const float4*>(&p[tid << 2]);
    float s = x.x + x.y + x.z + x.w;
    float ss = fmaf(x.x, x.x, fmaf(x.y, x.y, fmaf(x.z, x.z, x.w * x.w)));
#pragma unroll
    for (int off = 32; off > 0; off >>= 1) {
        s  += __shfl_down(s, off);
        ss += __shfl_down(ss, off);
    }
    __shared__ float rs[4], rss[4];
    int lane = tid & 63, wid = tid >> 6;
    if (lane == 0) { rs[wid] = s; rss[wid] = ss; }
    __syncthreads();
    float S = rs[0] + rs[1] + rs[2] + rs[3];
    float SS = rss[0] + rss[1] + rss[2] + rss[3];
    float mu = S * (1.0f / 1024.0f);
    float var = SS * (1.0f / 1024.0f) - mu * mu;
    float rstd = rsqrtf(var + 1e-12f);
    float4 g = *reinterpret_cast<const float4*>(&gamma[tid << 2]);
    float4 be = *reinterpret_cast<const float4*>(&beta[tid << 2]);
    float4 o;
    o.x = (x.x - mu) * rstd * g.x + be.x;
    o.y = (x.y - mu) * rstd * g.y + be.y;
    o.z = (x.z - mu) * rstd * g.z + be.z;
    o.w = (x.w - mu) * rstd * g.w + be.w;
    *reinterpret_cast<float4*>(&p[tid << 2]) = o;
}

// ---------------- launch ----------------
extern "C" void kernel_launch(void* const* d_in, const int* in_sizes, int n_in,
                              void* d_out, int out_size, void* d_ws, size_t ws_size,
                              hipStream_t stream)
{
    (void)in_sizes; (void)n_in; (void)out_size; (void)ws_size;
    const float* hidden = (const float*)d_in[0];
    const float* Wq = (const float*)d_in[1];
    const float* bq = (const float*)d_in[2];
    const float* Wk = (const float*)d_in[3];
    const float* bk = (const float*)d_in[4];
    const float* Wv = (const float*)d_in[5];
    const float* bv = (const float*)d_in[6];
    const float* Wo = (const float*)d_in[7];
    const float* bo = (const float*)d_in[8];
    const float* g  = (const float*)d_in[9];
    const float* be = (const float*)d_in[10];
    float* out = (float*)d_out;

    // workspace layout (Wqt/Wkt/Wvt contiguous => one [2048][1024] B^T matrix)
    u16* hb  = (u16*)d_ws;                       // [8192][1024] bf16 hidden
    u16* Wqt = hb  + (size_t)8192 * 1024;        // [1024][1024] Wq^T
    u16* Wkt = Wqt + (size_t)1024 * 1024;        // [512][1024]  Wk^T
    u16* Wvt = Wkt + (size_t)512 * 1024;         // [512][1024]  Wv^T
    u16* Wot = Wvt + (size_t)512 * 1024;         // [1024][1024] Wo^T
    u16* Qb  = Wot + (size_t)1024 * 1024;        // [8192][1024] Q (then attn out)
    u16* Kb  = Qb  + (size_t)8192 * 1024;        // [8192][512]  K
    u16* Vtb = Kb  + (size_t)8192 * 512;         // [4096][1024] V^T per (b,kvh)
    // total ~66 MB

    cvt_all_kernel<<<9216, 256, 0, stream>>>(hidden, hb, Wq, Wk, Wv, Wo,
                                             Wqt, Wkt, Wvt, Wot);

    // fused QKV: 256^2 tile, grid 256 = 1 block/CU, static 128 KB LDS
    gemm_qkv<<<256, 512, 0, stream>>>(hb, Wqt, bq, bk, bv, Qb, Kb, Vtb);

    // RoPE on K only (Q roped inside attn)
    rope_bf16_kernel<<<2048, 256, 0, stream>>>(Kb);

    attn_mfma<<<dim3(1024), 256, 0, stream>>>(Qb, Kb, Vtb, Qb);

    // out-proj: fp32 out + bias + resid, 2-phase pipelined
    gemm_out<<<dim3(512), 256, 0, stream>>>(Qb, Wot, bo, hidden, out);

    ln_kernel<<<8192, 256, 0, stream>>>(out, g, be);
}

// Round 10
// 227.162 us; speedup vs baseline: 2.0720x; 1.0290x over previous
//
#include <hip/hip_runtime.h>
#include <math.h>
#include <stdint.h>

typedef unsigned short u16;
typedef __bf16 bf16x8 __attribute__((ext_vector_type(8)));
typedef float f32x4 __attribute__((ext_vector_type(4)));

typedef const __attribute__((address_space(1))) void gv_t;
typedef __attribute__((address_space(3))) void lv_t;

__device__ __forceinline__ u16 f2bf(float f) {
    unsigned u = __builtin_bit_cast(unsigned, f);
    return (u16)((u + 0x7FFFu + ((u >> 16) & 1u)) >> 16);
}
__device__ __forceinline__ float bf2f(u16 h) {
    return __builtin_bit_cast(float, (unsigned)h << 16);
}
// async global->LDS, 16B per lane; LDS dest = wave-uniform base + lane*16
__device__ __forceinline__ void gll16(const void* g, void* l) {
    __builtin_amdgcn_global_load_lds((gv_t*)(uintptr_t)g,
                                     (lv_t*)(unsigned)(uintptr_t)l, 16, 0, 0);
}

// ---------------- fused conversions: hidden fp32->bf16 + 4 weight transposes ----
__global__ __launch_bounds__(256) void cvt_all_kernel(
    const float* __restrict__ hidden, u16* __restrict__ hb,
    const float* __restrict__ w0, const float* __restrict__ w1,
    const float* __restrict__ w2, const float* __restrict__ w3,
    u16* __restrict__ o0, u16* __restrict__ o1,
    u16* __restrict__ o2, u16* __restrict__ o3)
{
    __shared__ u16 t[64][65];
    int bid = blockIdx.x, tid = threadIdx.x;
    if (bid < 8192) {
        int i = bid * 256 + tid;
        float4 f = ((const float4*)hidden)[i];
        ushort4 o = make_ushort4(f2bf(f.x), f2bf(f.y), f2bf(f.z), f2bf(f.w));
        ((ushort4*)hb)[i] = o;
        return;
    }
    int id2 = bid - 8192;                 // 1024 t4 blocks
    int bz = id2 >> 8, by = (id2 >> 4) & 15, bx = id2 & 15;
    const float* in; u16* out; int N;
    switch (bz) {
        case 0: in = w0; out = o0; N = 1024; break;
        case 1: in = w1; out = o1; N = 512;  break;
        case 2: in = w2; out = o2; N = 512;  break;
        default: in = w3; out = o3; N = 1024; break;
    }
    int kb = by * 64, nb = bx * 64;
    if (nb >= N) return;
#pragma unroll
    for (int c = 0; c < 16; ++c) {
        int id = c * 256 + tid;
        int r = id >> 6, n = id & 63;
        t[n][r] = f2bf(in[(size_t)(kb + r) * N + nb + n]);
    }
    __syncthreads();
#pragma unroll
    for (int c = 0; c < 16; ++c) {
        int id = c * 256 + tid;
        int r = id >> 6, n = id & 63;
        out[(size_t)(nb + r) * 1024 + kb + n] = t[r][n];
    }
}

// ---------------- 256x256 fused-QKV GEMM: 8-phase counted-vmcnt schedule -----
// A [8192][1024] bf16, Bt [2048][1024] bf16. 8 waves (2Mx4N), wave tile 128x64.
// Grid 256 = 1 block/CU. LDS 128 KB static: buffers by K-tile PARITY
// (buf0=even tiles, buf1=odd). Iteration m computes tiles (2m, 2m+1) as
// 8 phases; each phase: {4 af ds_reads (+8 bfr at P1/P5) -> stage one
// half-tile (2 gll16) -> s_barrier -> setprio(1) -> 16 MFMA -> setprio(0)
// -> s_barrier}. Counted waits ONLY at P4/P8: vmcnt(4) (loads stay in
// flight across barriers - T3+T4, m198/m218). Stage placement derived from
// consumption: B-frags of a tile read once (P1/P5) -> its halves free next
// phase; A-quarters read across 4 phases -> halves free after P4/P8.
//   P1: A(t+1)h0   P2: A(t+1)h1, B(t+2)h0   P3: B(t+2)h1   P4: wait(4)
//   P5: A(t+2)h0   P6: A(t+2)h1             P7: B(t+3)h0   P8: B(t+3)h1, wait(4)
// Last iteration stages only A(15) and drains with vmcnt(0) (static counts
// shift when stages are skipped). All branches wave-uniform.
// Epilogue: cols 0-1023 -> Qo(b0); 1024-1535 -> Ko(b1); 1536-2047 -> V
// transposed to Vto[((b*8+kvh)*64+d)*1024+s] (b2).
__global__ __launch_bounds__(512, 2) void gemm_qkv(
    const u16* __restrict__ A, const u16* __restrict__ Bt,
    const float* __restrict__ b0, const float* __restrict__ b1,
    const float* __restrict__ b2,
    u16* __restrict__ Qo, u16* __restrict__ Ko, u16* __restrict__ Vto)
{
    __shared__ __align__(16) u16 Asl[2][256 * 64];   // 64 KB
    __shared__ __align__(16) u16 Bsl[2][256 * 64];   // 64 KB
    const int tid = threadIdx.x, lane = tid & 63, w = tid >> 6;  // w 0..7
    const int quad = lane >> 4, l16 = lane & 15;
    const int id = blockIdx.x;
    const int nid = (id & 7) * 32 + (id >> 3);    // XCD-chunked (id%8 -> XCD)
    const int bx = nid & 7, by = nid >> 3;
    const int bm = by * 256, bn = bx * 256;
    const int wm = (w >> 2) * 128, wn = (w & 3) * 64;   // 2M x 4N waves

    f32x4 acc[8][4] = {};   // 128 VGPR

    const int dr = lane >> 3;                       // row within 8-row band
    const int dcs = (((lane & 7) ^ dr) << 3);       // swizzled global chunk (elems)
    const int sw = l16 & 7;                         // fragment-read swizzle

    // stage one half-tile (128 rows x 64 k) of A or B for K-tile t, half h.
    // dest elem offset = rowbase*64 + lane*8 (wave-uniform base + lane*16B);
    // source carries the XOR chunk swizzle per 8-row band (matches sw reads).
    auto stA = [&](int t, int h) {
#pragma unroll
        for (int c = 0; c < 2; ++c) {
            int rb = h * 128 + c * 64 + w * 8;
            gll16(&A[(size_t)(bm + rb + dr) * 1024 + t * 64 + dcs],
                  &Asl[t & 1][rb * 64]);
        }
    };
    auto stB = [&](int t, int h) {
#pragma unroll
        for (int c = 0; c < 2; ++c) {
            int rb = h * 128 + c * 64 + w * 8;
            gll16(&Bt[(size_t)(bn + rb + dr) * 1024 + t * 64 + dcs],
                  &Bsl[t & 1][rb * 64]);
        }
    };

    // prologue: A(0) both halves, B(0) both, B(1) both; full drain.
    stA(0, 0); stA(0, 1); stB(0, 0); stB(0, 1); stB(1, 0); stB(1, 1);
    __syncthreads();

    for (int m = 0; m < 8; ++m) {
        const int t0 = 2 * m;
        const bool nf = (m < 7);   // not-final iteration
#pragma unroll
        for (int half = 0; half < 2; ++half) {
            const int tt = t0 + half;
            const u16* Ab = Asl[tt & 1];
            const u16* Bb = Bsl[tt & 1];
            bf16x8 bfr[4][2];
#pragma unroll
            for (int p = 0; p < 4; ++p) {
                // ---- ds-reads for this phase's MFMA cluster
                bf16x8 af[2][2];
#pragma unroll
                for (int ii = 0; ii < 2; ++ii)
#pragma unroll
                    for (int ks = 0; ks < 2; ++ks)
                        af[ii][ks] = *(const bf16x8*)&Ab[(wm + (2 * p + ii) * 16 + l16) * 64 + (((ks * 4 + quad) ^ sw) << 3)];
                if (p == 0) {
#pragma unroll
                    for (int j = 0; j < 4; ++j)
#pragma unroll
                        for (int ks = 0; ks < 2; ++ks)
                            bfr[j][ks] = *(const bf16x8*)&Bb[(wn + j * 16 + l16) * 64 + (((ks * 4 + quad) ^ sw) << 3)];
                }
                // ---- stage issue per phase table (ph = half*4+p, 0-based)
                const int ph = half * 4 + p;
                if (ph == 0) { stA(t0 + 1, 0); }
                else if (ph == 1) { stA(t0 + 1, 1); if (nf) stB(t0 + 2, 0); }
                else if (ph == 2) { if (nf) stB(t0 + 2, 1); }
                else if (ph == 4) { if (nf) stA(t0 + 2, 0); }
                else if (ph == 5) { if (nf) stA(t0 + 2, 1); }
                else if (ph == 6) { if (nf) stB(t0 + 3, 0); }
                else if (ph == 7) { if (nf) stB(t0 + 3, 1); }
                // ---- counted waits at P4 / P8 only
                if (ph == 3 || ph == 7) {
                    if (nf) asm volatile("s_waitcnt vmcnt(4)" ::: "memory");
                    else    asm volatile("s_waitcnt vmcnt(0)" ::: "memory");
                }
                __builtin_amdgcn_s_barrier();
                __builtin_amdgcn_s_setprio(1);
#pragma unroll
                for (int ii = 0; ii < 2; ++ii)
#pragma unroll
                    for (int j = 0; j < 4; ++j)
#pragma unroll
                        for (int ks = 0; ks < 2; ++ks)
                            acc[2 * p + ii][j] = __builtin_amdgcn_mfma_f32_16x16x32_bf16(
                                af[ii][ks], bfr[j][ks], acc[2 * p + ii][j], 0, 0, 0);
                __builtin_amdgcn_s_setprio(0);
                __builtin_amdgcn_s_barrier();
            }
        }
    }

    // epilogue: C/D layout col=lane&15, row=quad*4+reg. 256-col block ranges
    // never straddle the 1024/1536 boundaries (all multiples of 256).
#pragma unroll
    for (int j = 0; j < 4; ++j) {
        int col = bn + wn + j * 16 + l16;
        if (col < 1024) {
            float bb = b0[col];
#pragma unroll
            for (int i = 0; i < 8; ++i) {
                int row0 = bm + wm + i * 16 + quad * 4;
#pragma unroll
                for (int r = 0; r < 4; ++r)
                    Qo[(size_t)(row0 + r) * 1024 + col] = f2bf(acc[i][j][r] + bb);
            }
        } else if (col < 1536) {
            int c2 = col - 1024;
            float bb = b1[c2];
#pragma unroll
            for (int i = 0; i < 8; ++i) {
                int row0 = bm + wm + i * 16 + quad * 4;
#pragma unroll
                for (int r = 0; r < 4; ++r)
                    Ko[(size_t)(row0 + r) * 512 + c2] = f2bf(acc[i][j][r] + bb);
            }
        } else {
            int c2 = col - 1536, kvh = c2 >> 6, d = c2 & 63;
            float bb = b2[c2];
#pragma unroll
            for (int i = 0; i < 8; ++i) {
                int row0 = bm + wm + i * 16 + quad * 4;
                int b = row0 >> 10, s = row0 & 1023;
                ushort4 o4;
                o4.x = f2bf(acc[i][j][0] + bb);
                o4.y = f2bf(acc[i][j][1] + bb);
                o4.z = f2bf(acc[i][j][2] + bb);
                o4.w = f2bf(acc[i][j][3] + bb);
                *(ushort4*)&Vto[(size_t)((b * 8 + kvh) * 64 + d) * 1024 + s] = o4;
            }
        }
    }
}

// ---------------- out-proj GEMM (proven R3 2-phase, 128x128, unchanged) -----
// NOTE (R6 lesson): no sincos/extra math in this epilogue — spills acc.
__global__ __launch_bounds__(256) void gemm_out(
    const u16* __restrict__ A, const u16* __restrict__ Bt,
    const float* __restrict__ b0,
    const float* __restrict__ resid, float* __restrict__ Cf)
{
    __shared__ __align__(16) u16 Asl[2][128 * 64];
    __shared__ __align__(16) u16 Bsl[2][128 * 64];
    const int tid = threadIdx.x, lane = tid & 63, w = tid >> 6;
    const int quad = lane >> 4, l16 = lane & 15;
    const int id = blockIdx.x;
    const int nid = (id & 7) * 64 + (id >> 3);     // XCD-chunked, 512 blocks
    const int bx = nid & 7, by = nid >> 3;
    const int bm = by * 128, bn = bx * 128;
    const int wm = (w >> 1) * 64, wn = (w & 1) * 64;
    const int K = 1024, N = 1024;

    f32x4 acc[4][4] = {};

    const int dr = lane >> 3;
    const int dcs = (((lane & 7) ^ dr) << 3);
    const u16* Ag = &A[(size_t)(bm + w * 32 + dr) * K + dcs];
    const u16* Bg = &Bt[(size_t)(bn + w * 32 + dr) * K + dcs];
    const int sw = l16 & 7;

#pragma unroll
    for (int c = 0; c < 4; ++c) {
        gll16(Ag + (size_t)(c * 8) * K, &Asl[0][(w * 32 + c * 8) * 64]);
        gll16(Bg + (size_t)(c * 8) * K, &Bsl[0][(w * 32 + c * 8) * 64]);
    }
    for (int t = 0; t < 16; ++t) {
        const int cur = t & 1;
        __syncthreads();
        if (t < 15) {
            const int k0 = (t + 1) * 64;
#pragma unroll
            for (int c = 0; c < 4; ++c) {
                gll16(Ag + (size_t)(c * 8) * K + k0, &Asl[cur ^ 1][(w * 32 + c * 8) * 64]);
                gll16(Bg + (size_t)(c * 8) * K + k0, &Bsl[cur ^ 1][(w * 32 + c * 8) * 64]);
            }
        }
        bf16x8 af[4][2], bfr[4][2];
#pragma unroll
        for (int i = 0; i < 4; ++i)
#pragma unroll
            for (int ks = 0; ks < 2; ++ks)
                af[i][ks] = *(const bf16x8*)&Asl[cur][(wm + i * 16 + l16) * 64 + (((ks * 4 + quad) ^ sw) << 3)];
#pragma unroll
        for (int j = 0; j < 4; ++j)
#pragma unroll
            for (int ks = 0; ks < 2; ++ks)
                bfr[j][ks] = *(const bf16x8*)&Bsl[cur][(wn + j * 16 + l16) * 64 + (((ks * 4 + quad) ^ sw) << 3)];
#pragma unroll
        for (int i = 0; i < 4; ++i)
#pragma unroll
            for (int j = 0; j < 4; ++j)
#pragma unroll
                for (int ks = 0; ks < 2; ++ks)
                    acc[i][j] = __builtin_amdgcn_mfma_f32_16x16x32_bf16(af[i][ks], bfr[j][ks], acc[i][j], 0, 0, 0);
    }

#pragma unroll
    for (int j = 0; j < 4; ++j) {
        int col = bn + wn + j * 16 + l16;
        float bb = b0[col];
#pragma unroll
        for (int i = 0; i < 4; ++i) {
            int row0 = bm + wm + i * 16 + quad * 4;
#pragma unroll
            for (int r = 0; r < 4; ++r) {
                size_t off = (size_t)(row0 + r) * N + col;
                Cf[off] = acc[i][j][r] + bb + resid[off];
            }
        }
    }
}

// ---------------- RoPE (interleaved), in place on bf16 K, 4 pairs/thread ----
__global__ __launch_bounds__(256) void rope_bf16_kernel(u16* __restrict__ x)
{
    int idx = blockIdx.x * 256 + threadIdx.x;   // 524288 total
    int jg = idx & 7;                           // group of 4 pairs
    int h = (idx >> 3) & 7;                     // kvh
    int row = idx >> 6;
    float fpos = (float)(row & 1023);
    uint4 u4 = *(uint4*)&x[(size_t)row * 512 + h * 64 + jg * 8];
    unsigned* uw = &u4.x;
#pragma unroll
    for (int t = 0; t < 4; ++t) {
        int j = jg * 4 + t;
        float inv = exp2f((float)j * -0.4152410118609203f);  // 10000^(-2j/64)
        float sn, cs;
        sincosf(fpos * inv, &sn, &cs);
        unsigned u = uw[t];
        float x1 = bf2f((u16)(u & 0xffff)), x2 = bf2f((u16)(u >> 16));
        float y1 = x1 * cs - x2 * sn, y2 = x1 * sn + x2 * cs;
        uw[t] = (unsigned)f2bf(y1) | ((unsigned)f2bf(y2) << 16);
    }
    *(uint4*)&x[(size_t)row * 512 + h * 64 + jg * 8] = u4;
}

// ---------------- MFMA flash attention: 128 q/block, fused Q-RoPE -----------
// R4-proven version (53-54 us), unchanged.
__global__ __launch_bounds__(256, 4) void attn_mfma(
    const u16* __restrict__ Q, const u16* __restrict__ K,
    const u16* __restrict__ Vt, u16* __restrict__ O)
{
    __shared__ __align__(16) u16 Ks[2][64 * 64];   // [buf][key][d], swizzled chunks
    __shared__ __align__(16) u16 Vts[2][64 * 64];  // [buf][d][key], swizzled chunks
    __shared__ __align__(16) u16 Ps[64][40];       // [wave 16-row band][32 keys + pad]

    const int tid = threadIdx.x, lane = tid & 63, w = tid >> 6;
    const int quad = lane >> 4, l16 = lane & 15;
    const int id = blockIdx.x;
    const int nid = (id & 7) * 128 + (id >> 3);    // XCD-chunked (id%8 -> XCD)
    const int qt = nid & 7, h = (nid >> 3) & 15, b = nid >> 7;
    const int kvh = h >> 1;
    const size_t qrow0 = (size_t)b * 1024 + qt * 128;
    const size_t krow0 = (size_t)b * 1024;
    const u16* Vg = Vt + (size_t)((b * 8 + kvh) * 64) * 1024;

    const int dr = lane >> 3;
    const int dcs = (((lane & 7) ^ dr) << 3);
    const u16* Kg0 = &K[(krow0 + w * 16 + dr) * 512 + kvh * 64 + dcs];
    const u16* Vg0 = &Vg[(size_t)(w * 16 + dr) * 1024 + dcs];
    const int sw = l16 & 7;
    const float C1 = 0.18033688011112043f;  // 0.125 * log2(e), folded into Q

#pragma unroll
    for (int c = 0; c < 2; ++c) {
        gll16(Kg0 + (size_t)(c * 8) * 512, &Ks[0][(w * 16 + c * 8) * 64]);
        gll16(Vg0 + (size_t)(c * 8) * 1024, &Vts[0][(w * 16 + c * 8) * 64]);
    }

    bf16x8 qf[2][2];
#pragma unroll
    for (int qg = 0; qg < 2; ++qg) {
        int qrow = w * 32 + qg * 16 + l16;
        float fpos = (float)(qt * 128 + qrow);
#pragma unroll
        for (int ks = 0; ks < 2; ++ks) {
            uint4 qraw = *(const uint4*)&Q[(qrow0 + qrow) * 1024 + h * 64 + ks * 32 + quad * 8];
            unsigned o_[4];
#pragma unroll
            for (int t = 0; t < 4; ++t) {
                int j = ks * 16 + quad * 4 + t;
                float inv = exp2f((float)j * -0.4152410118609203f);
                float sn_, cs_;
                sincosf(fpos * inv, &sn_, &cs_);
                cs_ *= C1; sn_ *= C1;            // fold softmax scale into Q
                unsigned u = (&qraw.x)[t];
                float x1 = bf2f((u16)(u & 0xffff)), x2 = bf2f((u16)(u >> 16));
                float y1 = x1 * cs_ - x2 * sn_, y2 = x1 * sn_ + x2 * cs_;
                o_[t] = (unsigned)f2bf(y1) | ((unsigned)f2bf(y2) << 16);
            }
            qf[qg][ks] = __builtin_bit_cast(bf16x8, make_uint4(o_[0], o_[1], o_[2], o_[3]));
        }
    }

    f32x4 acc_o[2][4] = {};
    f32x4 lsum[2] = {};  // ones-MFMA row-sum accumulator
    const bf16x8 ones = __builtin_bit_cast(bf16x8,
        make_uint4(0x3F803F80u, 0x3F803F80u, 0x3F803F80u, 0x3F803F80u));

    for (int kt = 0; kt < 16; ++kt) {
        const int cur = kt & 1;
        __syncthreads();

        if (kt < 15) {
#pragma unroll
            for (int c = 0; c < 2; ++c) {
                gll16(Kg0 + (size_t)((kt + 1) * 64 + c * 8) * 512,
                      &Ks[cur ^ 1][(w * 16 + c * 8) * 64]);
                gll16(Vg0 + (size_t)(c * 8) * 1024 + (kt + 1) * 64,
                      &Vts[cur ^ 1][(w * 16 + c * 8) * 64]);
            }
        }

        f32x4 s[2][4] = {};
        __builtin_amdgcn_s_setprio(1);
#pragma unroll
        for (int ks = 0; ks < 2; ++ks) {
#pragma unroll
            for (int nt = 0; nt < 4; ++nt) {
                bf16x8 ak = *(const bf16x8*)&Ks[cur][(nt * 16 + l16) * 64 + (((ks * 4 + quad) ^ sw) << 3)];
                s[0][nt] = __builtin_amdgcn_mfma_f32_16x16x32_bf16(ak, qf[0][ks], s[0][nt], 0, 0, 0);
                s[1][nt] = __builtin_amdgcn_mfma_f32_16x16x32_bf16(ak, qf[1][ks], s[1][nt], 0, 0, 0);
            }
        }
        __builtin_amdgcn_s_setprio(0);

#pragma unroll
        for (int kc = 0; kc < 2; ++kc) {
            bf16x8 av[4];  // V fragments cached: shared by both q-groups
#pragma unroll
            for (int nt = 0; nt < 4; ++nt)
                av[nt] = *(const bf16x8*)&Vts[cur][(nt * 16 + l16) * 64 + (((kc * 4 + quad) ^ sw) << 3)];
#pragma unroll
            for (int qg = 0; qg < 2; ++qg) {
#pragma unroll
                for (int ntl = 0; ntl < 2; ++ntl) {
                    int nt = kc * 2 + ntl;
                    float p0 = __builtin_amdgcn_exp2f(s[qg][nt][0]);
                    float p1 = __builtin_amdgcn_exp2f(s[qg][nt][1]);
                    unsigned pk0 = __builtin_amdgcn_perm(
                        __builtin_bit_cast(unsigned, p1),
                        __builtin_bit_cast(unsigned, p0), 0x07060302u);
                    float p2 = __builtin_amdgcn_exp2f(s[qg][nt][2]);
                    float p3 = __builtin_amdgcn_exp2f(s[qg][nt][3]);
                    unsigned pk1 = __builtin_amdgcn_perm(
                        __builtin_bit_cast(unsigned, p3),
                        __builtin_bit_cast(unsigned, p2), 0x07060302u);
                    *(uint2*)&Ps[w * 16 + l16][ntl * 16 + quad * 4] = make_uint2(pk0, pk1);
                }
                bf16x8 bp = *(const bf16x8*)&Ps[w * 16 + l16][quad * 8];
                __builtin_amdgcn_s_setprio(1);
                lsum[qg] = __builtin_amdgcn_mfma_f32_16x16x32_bf16(ones, bp, lsum[qg], 0, 0, 0);
#pragma unroll
                for (int nt = 0; nt < 4; ++nt)
                    acc_o[qg][nt] = __builtin_amdgcn_mfma_f32_16x16x32_bf16(av[nt], bp, acc_o[qg][nt], 0, 0, 0);
                __builtin_amdgcn_s_setprio(0);
            }
        }
    }

#pragma unroll
    for (int qg = 0; qg < 2; ++qg) {
        float rl = 1.0f / lsum[qg][0];
        size_t orow = (qrow0 + w * 32 + qg * 16 + l16) * 1024 + h * 64;
#pragma unroll
        for (int nt = 0; nt < 4; ++nt) {
            ushort4 o4;
            o4.x = f2bf(acc_o[qg][nt][0] * rl);
            o4.y = f2bf(acc_o[qg][nt][1] * rl);
            o4.z = f2bf(acc_o[qg][nt][2] * rl);
            o4.w = f2bf(acc_o[qg][nt][3] * rl);
            *(ushort4*)&O[orow + nt * 16 + quad * 4] = o4;
        }
    }
}

// ---------------- LayerNorm in place on [8192][1024] fp32 ----------------
__global__ __launch_bounds__(256) void ln_kernel(float* __restrict__ io,
    const float* __restrict__ gamma, const float* __restrict__ beta)
{
    int row = blockIdx.x;
    int tid = threadIdx.x;
    float* p = io + (size_t)row * 1024;
    float4 x = *reinterpret_cast<const float4*>(&p[tid << 2]);
    float s = x.x + x.y + x.z + x.w;
    float ss = fmaf(x.x, x.x, fmaf(x.y, x.y, fmaf(x.z, x.z, x.w * x.w)));
#pragma unroll
    for (int off = 32; off > 0; off >>= 1) {
        s  += __shfl_down(s, off);
        ss += __shfl_down(ss, off);
    }
    __shared__ float rs[4], rss[4];
    int lane = tid & 63, wid = tid >> 6;
    if (lane == 0) { rs[wid] = s; rss[wid] = ss; }
    __syncthreads();
    float S = rs[0] + rs[1] + rs[2] + rs[3];
    float SS = rss[0] + rss[1] + rss[2] + rss[3];
    float mu = S * (1.0f / 1024.0f);
    float var = SS * (1.0f / 1024.0f) - mu * mu;
    float rstd = rsqrtf(var + 1e-12f);
    float4 g = *reinterpret_cast<const float4*>(&gamma[tid << 2]);
    float4 be = *reinterpret_cast<const float4*>(&beta[tid << 2]);
    float4 o;
    o.x = (x.x - mu) * rstd * g.x + be.x;
    o.y = (x.y - mu) * rstd * g.y + be.y;
    o.z = (x.z - mu) * rstd * g.z + be.z;
    o.w = (x.w - mu) * rstd * g.w + be.w;
    *reinterpret_cast<float4*>(&p[tid << 2]) = o;
}

// ---------------- launch ----------------
extern "C" void kernel_launch(void* const* d_in, const int* in_sizes, int n_in,
                              void* d_out, int out_size, void* d_ws, size_t ws_size,
                              hipStream_t stream)
{
    (void)in_sizes; (void)n_in; (void)out_size; (void)ws_size;
    const float* hidden = (const float*)d_in[0];
    const float* Wq = (const float*)d_in[1];
    const float* bq = (const float*)d_in[2];
    const float* Wk = (const float*)d_in[3];
    const float* bk = (const float*)d_in[4];
    const float* Wv = (const float*)d_in[5];
    const float* bv = (const float*)d_in[6];
    const float* Wo = (const float*)d_in[7];
    const float* bo = (const float*)d_in[8];
    const float* g  = (const float*)d_in[9];
    const float* be = (const float*)d_in[10];
    float* out = (float*)d_out;

    // workspace layout (Wqt/Wkt/Wvt contiguous => one [2048][1024] B^T matrix)
    u16* hb  = (u16*)d_ws;                       // [8192][1024] bf16 hidden
    u16* Wqt = hb  + (size_t)8192 * 1024;        // [1024][1024] Wq^T
    u16* Wkt = Wqt + (size_t)1024 * 1024;        // [512][1024]  Wk^T
    u16* Wvt = Wkt + (size_t)512 * 1024;         // [512][1024]  Wv^T
    u16* Wot = Wvt + (size_t)512 * 1024;         // [1024][1024] Wo^T
    u16* Qb  = Wot + (size_t)1024 * 1024;        // [8192][1024] Q (then attn out)
    u16* Kb  = Qb  + (size_t)8192 * 1024;        // [8192][512]  K
    u16* Vtb = Kb  + (size_t)8192 * 512;         // [4096][1024] V^T per (b,kvh)
    // total ~66 MB

    cvt_all_kernel<<<9216, 256, 0, stream>>>(hidden, hb, Wq, Wk, Wv, Wo,
                                             Wqt, Wkt, Wvt, Wot);

    // fused QKV: 256^2 tile, 8-phase counted-vmcnt schedule, 1 block/CU
    gemm_qkv<<<256, 512, 0, stream>>>(hb, Wqt, bq, bk, bv, Qb, Kb, Vtb);

    // RoPE on K only (Q roped inside attn)
    rope_bf16_kernel<<<2048, 256, 0, stream>>>(Kb);

    attn_mfma<<<dim3(1024), 256, 0, stream>>>(Qb, Kb, Vtb, Qb);

    // out-proj: fp32 out + bias + resid, 2-phase pipelined
    gemm_out<<<dim3(512), 256, 0, stream>>>(Qb, Wot, bo, hidden, out);

    ln_kernel<<<8192, 256, 0, stream>>>(out, g, be);
}